// Round 19
// baseline (191.518 us; speedup 1.0000x reference)
//
#include <hip/hip_runtime.h>
#include <hip/hip_bf16.h>
#include <math.h>

#define S_LEN 2048
#define DMODEL 1024
#define NHEAD 16
#define DHEAD 64
#define BATCH 4
#define MROWS (BATCH * S_LEN)  // 8192

typedef unsigned short u16;
typedef __attribute__((ext_vector_type(4))) unsigned short u16x4;
typedef __attribute__((ext_vector_type(8))) unsigned short u16x8;
typedef __attribute__((ext_vector_type(2))) unsigned u32x2;
typedef __attribute__((ext_vector_type(4))) unsigned u32x4;
typedef __attribute__((ext_vector_type(8))) short bf16x8;
typedef __attribute__((ext_vector_type(4))) float f32x4;

__device__ __forceinline__ u16 f2bf(float f) {
  unsigned u = __float_as_uint(f);
  u += 0x7fff + ((u >> 16) & 1);  // round-to-nearest-even
  return (u16)(u >> 16);
}

__device__ __forceinline__ unsigned pkbf2(float lo, float hi) {
  // single v_cvt_pk_bf16_f32: lo -> bits[15:0], hi -> bits[31:16]
  __hip_bfloat162 h = __float22bfloat162_rn(float2{lo, hi});
  unsigned r;
  __builtin_memcpy(&r, &h, 4);
  return r;
}

__device__ __forceinline__ float exp2v(float x) {  // raw v_exp_f32 (base-2)
  float r;
  asm("v_exp_f32 %0, %1" : "=v"(r) : "v"(x));
  return r;
}

__device__ __forceinline__ f32x4 mfma16(bf16x8 a, bf16x8 b, f32x4 c) {
  return __builtin_amdgcn_mfma_f32_16x16x32_bf16(a, b, c, 0, 0, 0);
}

// ---------------- fused cast fp32 -> bf16 (x + 4 weight matrices, one launch) ----------------
__global__ __launch_bounds__(256) void castall(
    const float* __restrict__ x,
    const float* __restrict__ w0, const float* __restrict__ w1,
    const float* __restrict__ w2, const float* __restrict__ w3,
    u16* __restrict__ ox,
    u16* __restrict__ o0, u16* __restrict__ o1,
    u16* __restrict__ o2, u16* __restrict__ o3) {
  const int blk = blockIdx.x;
  const float* in;
  u16* out;
  int base;
  if (blk < 4096)      { in = x;  out = ox; base = blk; }
  else if (blk < 4608) { in = w0; out = o0; base = blk - 4096; }
  else if (blk < 5120) { in = w1; out = o1; base = blk - 4608; }
  else if (blk < 5632) { in = w2; out = o2; base = blk - 5120; }
  else                 { in = w3; out = o3; base = blk - 5632; }
  const int i = (base * 256 + threadIdx.x) * 8;
  f32x4 v0 = *(const f32x4*)(in + i);
  f32x4 v1 = *(const f32x4*)(in + i + 4);
  u16x8 o;
#pragma unroll
  for (int j = 0; j < 4; ++j) { o[j] = f2bf(v0[j]); o[4 + j] = f2bf(v1[j]); }
  *(u16x8*)(out + i) = o;
}

// ---------------- QKV projection GEMM (BK=64, swizzled LDS, depth-2 reg-prefetch) ----------------
__global__ __launch_bounds__(256) void gemm_qkv(
    const u16* __restrict__ Xb,
    const u16* __restrict__ W0, const u16* __restrict__ W1, const u16* __restrict__ W2,
    const float* __restrict__ b0, const float* __restrict__ b1, const float* __restrict__ b2,
    u16* __restrict__ O0, u16* __restrict__ O1, u16* __restrict__ O2) {
  __shared__ u16 As[128 * 64];
  __shared__ u16 Bs[128 * 64];
  const int flat = blockIdx.x;
  const int xcd = flat & 7, idx = flat >> 3;   // 192 blocks per XCD
  const int ymt = xcd * 8 + idx / 24;          // m-tile 0..63
  const int rem = idx % 24;
  const int xnt = rem & 7;                     // n-tile 0..7
  const int z = rem >> 3;                      // 0..2 (Q/K/V)
  const u16* Wm = z == 0 ? W0 : (z == 1 ? W1 : W2);
  const float* bias = z == 0 ? b0 : (z == 1 ? b1 : b2);
  u16* Out = z == 0 ? O0 : (z == 1 ? O1 : O2);
  // Q pre-scale: (1/sqrt(64)) * log2(e), so attn scores are in log2 units
  const float qs = (z == 0) ? 0.18033688011112042f : 1.0f;
  const int tid = threadIdx.x;
  const int lane = tid & 63, g = lane >> 4, c = lane & 15;
  const int wave = tid >> 6;
  const int wm = wave >> 1, wn = wave & 1;
  const int bm0 = ymt * 128, bn0 = xnt * 128;

  // per-thread staging chunk geometry (invariant over k0): 4 chunks per matrix
  int srow[4], scol[4];
#pragma unroll
  for (int cc = 0; cc < 4; ++cc) {
    const int ci = cc * 256 + tid;          // chunk 0..1023
    srow[cc] = ci >> 3;
    scol[cc] = ((ci & 7) ^ (srow[cc] & 7)) << 3;  // inverse-swizzled source col
  }

  f32x4 acc[4][4];
#pragma unroll
  for (int m = 0; m < 4; ++m)
#pragma unroll
    for (int n = 0; n < 4; ++n) acc[m][n] = (f32x4){0.f, 0.f, 0.f, 0.f};

  u32x4 aA[4], bA[4], aB[4], bB[4];  // two staging sets (depth-2 pipeline)
#define GLOADA(k0_) do { _Pragma("unroll")                                     \
    for (int cc = 0; cc < 4; ++cc) {                                           \
      aA[cc] = *(const u32x4*)(Xb + (size_t)(bm0 + srow[cc]) * DMODEL + (k0_) + scol[cc]); \
      bA[cc] = *(const u32x4*)(Wm + (size_t)(bn0 + srow[cc]) * DMODEL + (k0_) + scol[cc]); \
    } } while (0)
#define GLOADB(k0_) do { _Pragma("unroll")                                     \
    for (int cc = 0; cc < 4; ++cc) {                                           \
      aB[cc] = *(const u32x4*)(Xb + (size_t)(bm0 + srow[cc]) * DMODEL + (k0_) + scol[cc]); \
      bB[cc] = *(const u32x4*)(Wm + (size_t)(bn0 + srow[cc]) * DMODEL + (k0_) + scol[cc]); \
    } } while (0)
#define WRITEA() do { _Pragma("unroll")                                        \
    for (int cc = 0; cc < 4; ++cc) {                                           \
      *(u32x4*)((char*)As + (cc * 256 + tid) * 16) = aA[cc];                   \
      *(u32x4*)((char*)Bs + (cc * 256 + tid) * 16) = bA[cc];                   \
    } } while (0)
#define WRITEB() do { _Pragma("unroll")                                        \
    for (int cc = 0; cc < 4; ++cc) {                                           \
      *(u32x4*)((char*)As + (cc * 256 + tid) * 16) = aB[cc];                   \
      *(u32x4*)((char*)Bs + (cc * 256 + tid) * 16) = bB[cc];                   \
    } } while (0)
#define COMPUTE() do { _Pragma("unroll")                                       \
    for (int ks = 0; ks < 2; ++ks) {                                           \
      bf16x8 af[4], bfr[4];                                                    \
      _Pragma("unroll")                                                        \
      for (int m = 0; m < 4; ++m) {                                            \
        const int arow = wm * 64 + m * 16 + c;                                 \
        af[m] = *(const bf16x8*)((const char*)As + arow * 128 +                \
                                 (((ks * 4 + g) ^ (arow & 7)) << 4));          \
      }                                                                        \
      _Pragma("unroll")                                                        \
      for (int n = 0; n < 4; ++n) {                                            \
        const int brow = wn * 64 + n * 16 + c;                                 \
        bfr[n] = *(const bf16x8*)((const char*)Bs + brow * 128 +               \
                                  (((ks * 4 + g) ^ (brow & 7)) << 4));         \
      }                                                                        \
      _Pragma("unroll")                                                        \
      for (int m = 0; m < 4; ++m)                                              \
        _Pragma("unroll")                                                      \
        for (int n = 0; n < 4; ++n)                                            \
          acc[m][n] = mfma16(af[m], bfr[n], acc[m][n]);                        \
    } } while (0)

  GLOADA(0);
  GLOADB(64);
  for (int k0 = 0; k0 < DMODEL; k0 += 128) {
    __syncthreads();
    WRITEA();
    __syncthreads();
    if (k0 + 128 < DMODEL) GLOADA(k0 + 128);
    COMPUTE();
    __syncthreads();
    WRITEB();
    __syncthreads();
    if (k0 + 192 < DMODEL) GLOADB(k0 + 192);
    COMPUTE();
  }
#undef GLOADA
#undef GLOADB
#undef WRITEA
#undef WRITEB
#undef COMPUTE
  if (z < 2) {
    // Q/K: (b,h,s,d) scatter
#pragma unroll
    for (int n = 0; n < 4; ++n) {
      const int coln = bn0 + wn * 64 + n * 16 + c;
      const float bn_ = bias[coln];
      const int h = coln >> 6, d = coln & 63;
#pragma unroll
      for (int m = 0; m < 4; ++m) {
#pragma unroll
        for (int r = 0; r < 4; ++r) {
          const int rowm = bm0 + wm * 64 + m * 16 + g * 4 + r;
          const int b_ = rowm >> 11, s_ = rowm & 2047;
          Out[(((size_t)(b_ * NHEAD + h) * S_LEN + s_) << 6) + d] =
              f2bf((acc[m][n][r] + bn_) * qs);
        }
      }
    }
  } else {
    // V^T: (b,h,d,s) — pack the 4 consecutive-s values into one 8B store
#pragma unroll
    for (int n = 0; n < 4; ++n) {
      const int coln = bn0 + wn * 64 + n * 16 + c;
      const float bn_ = bias[coln];
      const int h = coln >> 6, d = coln & 63;
#pragma unroll
      for (int m = 0; m < 4; ++m) {
        const int row0 = bm0 + wm * 64 + m * 16 + g * 4;
        const int b_ = row0 >> 11, s_ = row0 & 2047;
        u16x4 pk;
#pragma unroll
        for (int r = 0; r < 4; ++r) pk[r] = f2bf(acc[m][n][r] + bn_);
        *(u16x4*)(Out + ((size_t)(b_ * NHEAD + h) * DHEAD + d) * S_LEN + s_) = pk;
      }
    }
  }
}

// ---------------- output projection GEMM (BK=64, swizzled LDS, depth-2 reg-prefetch) ----------------
__global__ __launch_bounds__(256) void gemm_out(
    const u16* __restrict__ Ab, const u16* __restrict__ Wm,
    const float* __restrict__ bias, float* __restrict__ Out) {
  __shared__ u16 As[128 * 64];
  __shared__ u16 Bs[128 * 64];
  const int flat = blockIdx.x;
  const int xcd = flat & 7, idx = flat >> 3;   // 64 blocks per XCD
  const int ymt = xcd * 8 + (idx >> 3);        // m-tile 0..63
  const int xnt = idx & 7;                     // n-tile 0..7
  const int tid = threadIdx.x;
  const int lane = tid & 63, g = lane >> 4, c = lane & 15;
  const int wave = tid >> 6;
  const int wm = wave >> 1, wn = wave & 1;
  const int bm0 = ymt * 128, bn0 = xnt * 128;

  int srow[4], scol[4];
#pragma unroll
  for (int cc = 0; cc < 4; ++cc) {
    const int ci = cc * 256 + tid;
    srow[cc] = ci >> 3;
    scol[cc] = ((ci & 7) ^ (srow[cc] & 7)) << 3;
  }

  f32x4 acc[4][4];
#pragma unroll
  for (int m = 0; m < 4; ++m)
#pragma unroll
    for (int n = 0; n < 4; ++n) acc[m][n] = (f32x4){0.f, 0.f, 0.f, 0.f};

  u32x4 aA[4], bA[4], aB[4], bB[4];
#define GLOADA(k0_) do { _Pragma("unroll")                                     \
    for (int cc = 0; cc < 4; ++cc) {                                           \
      aA[cc] = *(const u32x4*)(Ab + (size_t)(bm0 + srow[cc]) * DMODEL + (k0_) + scol[cc]); \
      bA[cc] = *(const u32x4*)(Wm + (size_t)(bn0 + srow[cc]) * DMODEL + (k0_) + scol[cc]); \
    } } while (0)
#define GLOADB(k0_) do { _Pragma("unroll")                                     \
    for (int cc = 0; cc < 4; ++cc) {                                           \
      aB[cc] = *(const u32x4*)(Ab + (size_t)(bm0 + srow[cc]) * DMODEL + (k0_) + scol[cc]); \
      bB[cc] = *(const u32x4*)(Wm + (size_t)(bn0 + srow[cc]) * DMODEL + (k0_) + scol[cc]); \
    } } while (0)
#define WRITEA() do { _Pragma("unroll")                                        \
    for (int cc = 0; cc < 4; ++cc) {                                           \
      *(u32x4*)((char*)As + (cc * 256 + tid) * 16) = aA[cc];                   \
      *(u32x4*)((char*)Bs + (cc * 256 + tid) * 16) = bA[cc];                   \
    } } while (0)
#define WRITEB() do { _Pragma("unroll")                                        \
    for (int cc = 0; cc < 4; ++cc) {                                           \
      *(u32x4*)((char*)As + (cc * 256 + tid) * 16) = aB[cc];                   \
      *(u32x4*)((char*)Bs + (cc * 256 + tid) * 16) = bB[cc];                   \
    } } while (0)
#define COMPUTE() do { _Pragma("unroll")                                       \
    for (int ks = 0; ks < 2; ++ks) {                                           \
      bf16x8 af[4], bfr[4];                                                    \
      _Pragma("unroll")                                                        \
      for (int m = 0; m < 4; ++m) {                                            \
        const int arow = wm * 64 + m * 16 + c;                                 \
        af[m] = *(const bf16x8*)((const char*)As + arow * 128 +                \
                                 (((ks * 4 + g) ^ (arow & 7)) << 4));          \
      }                                                                        \
      _Pragma("unroll")                                                        \
      for (int n = 0; n < 4; ++n) {                                            \
        const int brow = wn * 64 + n * 16 + c;                                 \
        bfr[n] = *(const bf16x8*)((const char*)Bs + brow * 128 +               \
                                  (((ks * 4 + g) ^ (brow & 7)) << 4));         \
      }                                                                        \
      _Pragma("unroll")                                                        \
      for (int m = 0; m < 4; ++m)                                              \
        _Pragma("unroll")                                                      \
        for (int n = 0; n < 4; ++n)                                            \
          acc[m][n] = mfma16(af[m], bfr[n], acc[m][n]);                        \
    } } while (0)

  GLOADA(0);
  GLOADB(64);
  for (int k0 = 0; k0 < DMODEL; k0 += 128) {
    __syncthreads();
    WRITEA();
    __syncthreads();
    if (k0 + 128 < DMODEL) GLOADA(k0 + 128);
    COMPUTE();
    __syncthreads();
    WRITEB();
    __syncthreads();
    if (k0 + 192 < DMODEL) GLOADB(k0 + 192);
    COMPUTE();
  }
#undef GLOADA
#undef GLOADB
#undef WRITEA
#undef WRITEB
#undef COMPUTE
#pragma unroll
  for (int n = 0; n < 4; ++n) {
    const int coln = bn0 + wn * 64 + n * 16 + c;
    const float bn_ = bias[coln];
#pragma unroll
    for (int m = 0; m < 4; ++m) {
#pragma unroll
      for (int r = 0; r < 4; ++r) {
        const int rowm = bm0 + wm * 64 + m * 16 + g * 4 + r;
        Out[(size_t)rowm * DMODEL + coln] = acc[m][n][r] + bn_;
      }
    }
  }
}

// ---------------- causal flash attention (T14 reg-staging + l-from-MFMA) ----------------
__global__ __launch_bounds__(256) void attn_fwd(const u16* __restrict__ Qb,
                                                const u16* __restrict__ Kb,
                                                const u16* __restrict__ VTb,
                                                u16* __restrict__ AOb) {
  __shared__ u16 Kt[64 * 64];       // K tile [kv][d], swizzled chunks
  __shared__ u16 Vt[64 * 64];       // V^T tile [d][kv], swizzled chunks
  __shared__ unsigned Pl[4][16 * 36];  // per-wave P^T: row q=c (stride 36 u32 = 144B)
  const int tid = threadIdx.x;
  const int w = tid >> 6, lane = tid & 63, g = lane >> 4, c = lane & 15;
  const int flat = blockIdx.x;
  const int xcd = flat & 7, idx = flat >> 3;      // 256 blocks per XCD
  const int qt = 31 - (idx >> 3);                 // heavy tiles first
  const int bh = xcd * 8 + (idx & 7);             // 8 heads per XCD
  const size_t base = (size_t)bh * (S_LEN * DHEAD);  // same stride for K and VT
  const int b_ = bh >> 4, h = bh & 15;
  const int ci0 = w * 64 + lane;    // staging chunk index

  // per-thread staging chunk geometry (invariant over kt)
  const int row0_ = ci0 >> 3,            colg0 = (ci0 & 7) ^ (row0_ & 7);
  const int row1_ = (256 + ci0) >> 3,    colg1 = ((256 + ci0) & 7) ^ (row1_ & 7);

  const int qb = qt * 64;
  const int q = qb + w * 16 + c;   // this lane's q-row
  const bf16x8 qf0 = *(const bf16x8*)(Qb + base + (size_t)q * 64 + g * 8);
  const bf16x8 qf1 = *(const bf16x8*)(Qb + base + (size_t)q * 64 + 32 + g * 8);

  bf16x8 ones;
#pragma unroll
  for (int j = 0; j < 8; ++j) ones[j] = (short)0x3F80;  // bf16 1.0

  f32x4 oacc[4];
  f32x4 lacc = (f32x4){0.f, 0.f, 0.f, 0.f};
#pragma unroll
  for (int dt = 0; dt < 4; ++dt) oacc[dt] = (f32x4){0.f, 0.f, 0.f, 0.f};
  float m = -30000.f;

  u32x4 kreg0, kreg1, vreg0, vreg1;  // in-flight staging tile (64B/thread)
#define STAGE_LOAD(kt_) do {                                                  \
    const int kv0_ = (kt_) * 64;                                              \
    kreg0 = *(const u32x4*)(Kb + base + (size_t)(kv0_ + row0_) * 64 + colg0 * 8); \
    vreg0 = *(const u32x4*)(VTb + base + (size_t)row0_ * S_LEN + kv0_ + colg0 * 8); \
    kreg1 = *(const u32x4*)(Kb + base + (size_t)(kv0_ + row1_) * 64 + colg1 * 8); \
    vreg1 = *(const u32x4*)(VTb + base + (size_t)row1_ * S_LEN + kv0_ + colg1 * 8); \
  } while (0)

  const int nt = qt + 1;
  STAGE_LOAD(0);
  for (int kt = 0; kt < nt; ++kt) {
    const int kv0 = kt * 64;
    __syncthreads();  // prev tile's LDS reads done before overwrite
    // write staged regs -> LDS (compiler inserts vmcnt before first write)
    *(u32x4*)((char*)Kt + ci0 * 16) = kreg0;
    *(u32x4*)((char*)Vt + ci0 * 16) = vreg0;
    *(u32x4*)((char*)Kt + (256 + ci0) * 16) = kreg1;
    *(u32x4*)((char*)Vt + (256 + ci0) * 16) = vreg1;
    __syncthreads();  // tile ready
    if (kt + 1 < nt) STAGE_LOAD(kt + 1);  // issue next tile; hides under compute

    // S^T = K Q^T from swizzled LDS: s[t][r] = S[kv=kv0+16t+4g+r][q] (log2 units)
    f32x4 s[4];
#pragma unroll
    for (int t = 0; t < 4; ++t) {
      const int krow = t * 16 + c;
      const char* kbase = (const char*)Kt + krow * 128;
      bf16x8 kf0 = *(const bf16x8*)(kbase + ((g ^ (krow & 7)) * 16));
      bf16x8 kf1 = *(const bf16x8*)(kbase + (((4 + g) ^ (krow & 7)) * 16));
      f32x4 zacc = (f32x4){0.f, 0.f, 0.f, 0.f};
      zacc = mfma16(kf0, qf0, zacc);
      zacc = mfma16(kf1, qf1, zacc);
      s[t] = zacc;
    }
    if (kt == nt - 1) {  // diagonal tile only: causal mask
#pragma unroll
      for (int t = 0; t < 4; ++t)
#pragma unroll
        for (int r = 0; r < 4; ++r)
          if (kv0 + t * 16 + 4 * g + r > q) s[t][r] = -30000.f;
    }
    // row max via max3 tree (16 values) + 2-step cross-g reduce
    const float a0 = fmaxf(fmaxf(s[0][0], s[0][1]), s[0][2]);
    const float a1 = fmaxf(fmaxf(s[0][3], s[1][0]), s[1][1]);
    const float a2 = fmaxf(fmaxf(s[1][2], s[1][3]), s[2][0]);
    const float a3 = fmaxf(fmaxf(s[2][1], s[2][2]), s[2][3]);
    const float a4 = fmaxf(fmaxf(s[3][0], s[3][1]), s[3][2]);
    float pm = fmaxf(fmaxf(fmaxf(a0, a1), a2), fmaxf(fmaxf(a3, a4), s[3][3]));
    pm = fmaxf(pm, __shfl_xor(pm, 16));
    pm = fmaxf(pm, __shfl_xor(pm, 32));
    // defer-rescale (T13): only rescale when some row grew by > 2^8
    if (__any(pm > m + 8.0f)) {
      const float mn = fmaxf(m, pm);
      const float sc = exp2v(m - mn);
      lacc *= sc;
#pragma unroll
      for (int dt = 0; dt < 4; ++dt) oacc[dt] *= sc;
      m = mn;
    }
#pragma unroll
    for (int t = 0; t < 4; ++t) {
      const float p0 = exp2v(s[t][0] - m), p1 = exp2v(s[t][1] - m);
      const float p2 = exp2v(s[t][2] - m), p3 = exp2v(s[t][3] - m);
      // P^T[q=c][kv = 16t+4g+0..3]: two v_cvt_pk_bf16_f32, one 8B store
      u32x2 pk2;
      pk2[0] = pkbf2(p0, p1);
      pk2[1] = pkbf2(p2, p3);
      *(u32x2*)&Pl[w][c * 36 + t * 8 + g * 2] = pk2;
    }

    // O^T += V^T P^T ; l += ones^T P^T (MFMA, ones A-frag: every row = sum_kv P)
#pragma unroll
    for (int kk = 0; kk < 2; ++kk) {
      const bf16x8 pb = *(const bf16x8*)&Pl[w][c * 36 + kk * 16 + g * 4];
      lacc = mfma16(ones, pb, lacc);
#pragma unroll
      for (int dt = 0; dt < 4; ++dt) {
        const int vrow = dt * 16 + c;
        const bf16x8 vf = *(const bf16x8*)((const char*)Vt + vrow * 128 +
                                           (((kk * 4 + g) ^ (vrow & 7)) * 16));
        oacc[dt] = mfma16(vf, pb, oacc[dt]);
      }
    }
  }
#undef STAGE_LOAD
  // epilogue: lane owns O[q][d = dt*16 + 4g + 0..3] -> 8B packed stores
  const float inv = 1.0f / lacc[0];
  const size_t rowbase = ((size_t)(b_ * S_LEN + q) * DMODEL) + h * 64;
#pragma unroll
  for (int dt = 0; dt < 4; ++dt) {
    u16x4 pk4;
#pragma unroll
    for (int r = 0; r < 4; ++r) pk4[r] = f2bf(oacc[dt][r] * inv);
    *(u16x4*)(AOb + rowbase + dt * 16 + 4 * g) = pk4;
  }
}

extern "C" void kernel_launch(void* const* d_in, const int* in_sizes, int n_in,
                              void* d_out, int out_size, void* d_ws, size_t ws_size,
                              hipStream_t stream) {
  const float* x  = (const float*)d_in[0];
  const float* Wq = (const float*)d_in[1];
  const float* bq = (const float*)d_in[2];
  const float* Wk = (const float*)d_in[3];
  const float* bk = (const float*)d_in[4];
  const float* Wv = (const float*)d_in[5];
  const float* bv = (const float*)d_in[6];
  const float* Wo = (const float*)d_in[7];
  const float* bo = (const float*)d_in[8];
  float* out = (float*)d_out;
  char* ws = (char*)d_ws;

  const size_t MB = 1024 * 1024;
  u16* xb  = (u16*)(ws);              // 16 MB: x bf16 [8192][1024]
  u16* Wqb = (u16*)(ws + 16 * MB);    // 2 MB each
  u16* Wkb = (u16*)(ws + 18 * MB);
  u16* Wvb = (u16*)(ws + 20 * MB);
  u16* Wob = (u16*)(ws + 22 * MB);
  u16* Qb  = (u16*)(ws + 24 * MB);    // 16 MB (b,h,s,d), pre-scaled (log2 units)
  u16* Kb  = (u16*)(ws + 40 * MB);    // 16 MB (b,h,s,d)
  u16* VTb = (u16*)(ws + 56 * MB);    // 16 MB (b,h,d,s)
  u16* AOb = (u16*)(ws + 72 * MB);    // 16 MB (b,s,h*d)

  castall<<<6144, 256, 0, stream>>>(x, Wq, Wk, Wv, Wo, xb, Wqb, Wkb, Wvb, Wob);

  gemm_qkv<<<1536, 256, 0, stream>>>(
      xb, Wqb, Wkb, Wvb, bq, bk, bv, Qb, Kb, VTb);

  attn_fwd<<<2048, 256, 0, stream>>>(Qb, Kb, VTb, AOb);

  gemm_out<<<512, 256, 0, stream>>>(AOb, Wob, bo, out);
}

// Round 20
// 168.106 us; speedup vs baseline: 1.1393x; 1.1393x over previous
//
#include <hip/hip_runtime.h>
#include <hip/hip_bf16.h>
#include <math.h>

#define S_LEN 2048
#define DMODEL 1024
#define NHEAD 16
#define DHEAD 64
#define BATCH 4
#define MROWS (BATCH * S_LEN)  // 8192

typedef unsigned short u16;
typedef __attribute__((ext_vector_type(4))) unsigned short u16x4;
typedef __attribute__((ext_vector_type(8))) unsigned short u16x8;
typedef __attribute__((ext_vector_type(2))) unsigned u32x2;
typedef __attribute__((ext_vector_type(4))) unsigned u32x4;
typedef __attribute__((ext_vector_type(8))) short bf16x8;
typedef __attribute__((ext_vector_type(4))) float f32x4;

__device__ __forceinline__ u16 f2bf(float f) {
  unsigned u = __float_as_uint(f);
  u += 0x7fff + ((u >> 16) & 1);  // round-to-nearest-even
  return (u16)(u >> 16);
}

__device__ __forceinline__ unsigned pkbf2(float lo, float hi) {
  // single v_cvt_pk_bf16_f32: lo -> bits[15:0], hi -> bits[31:16]
  __hip_bfloat162 h = __float22bfloat162_rn(float2{lo, hi});
  unsigned r;
  __builtin_memcpy(&r, &h, 4);
  return r;
}

__device__ __forceinline__ float exp2v(float x) {  // raw v_exp_f32 (base-2)
  float r;
  asm("v_exp_f32 %0, %1" : "=v"(r) : "v"(x));
  return r;
}

__device__ __forceinline__ f32x4 mfma16(bf16x8 a, bf16x8 b, f32x4 c) {
  return __builtin_amdgcn_mfma_f32_16x16x32_bf16(a, b, c, 0, 0, 0);
}

// ---------------- fused cast fp32 -> bf16 (x + 4 weight matrices, one launch) ----------------
// blocks 0..4095 -> x (8192x1024); then 512-block ranges for Wq, Wk, Wv, Wo.
__global__ __launch_bounds__(256) void castall(
    const float* __restrict__ x,
    const float* __restrict__ w0, const float* __restrict__ w1,
    const float* __restrict__ w2, const float* __restrict__ w3,
    u16* __restrict__ ox,
    u16* __restrict__ o0, u16* __restrict__ o1,
    u16* __restrict__ o2, u16* __restrict__ o3) {
  const int blk = blockIdx.x;
  const float* in;
  u16* out;
  int base;
  if (blk < 4096)      { in = x;  out = ox; base = blk; }
  else if (blk < 4608) { in = w0; out = o0; base = blk - 4096; }
  else if (blk < 5120) { in = w1; out = o1; base = blk - 4608; }
  else if (blk < 5632) { in = w2; out = o2; base = blk - 5120; }
  else                 { in = w3; out = o3; base = blk - 5632; }
  const int i = (base * 256 + threadIdx.x) * 8;
  f32x4 v0 = *(const f32x4*)(in + i);
  f32x4 v1 = *(const f32x4*)(in + i + 4);
  u16x8 o;
#pragma unroll
  for (int j = 0; j < 4; ++j) { o[j] = f2bf(v0[j]); o[4 + j] = f2bf(v1[j]); }
  *(u16x8*)(out + i) = o;
}

// ---------------- QKV projection GEMM (BK=64, swizzled LDS, T14 reg-staging) ----------------
// Per K-step: write staged regs -> LDS between barriers, issue next step's
// global loads right after the tile barrier (latency hides under 32 MFMA).
__global__ __launch_bounds__(256) void gemm_qkv(
    const u16* __restrict__ Xb,
    const u16* __restrict__ W0, const u16* __restrict__ W1, const u16* __restrict__ W2,
    const float* __restrict__ b0, const float* __restrict__ b1, const float* __restrict__ b2,
    u16* __restrict__ O0, u16* __restrict__ O1, u16* __restrict__ O2) {
  __shared__ u16 As[128 * 64];
  __shared__ u16 Bs[128 * 64];
  const int flat = blockIdx.x;
  const int xcd = flat & 7, idx = flat >> 3;   // 192 blocks per XCD
  const int ymt = xcd * 8 + idx / 24;          // m-tile 0..63
  const int rem = idx % 24;
  const int xnt = rem & 7;                     // n-tile 0..7
  const int z = rem >> 3;                      // 0..2 (Q/K/V)
  const u16* Wm = z == 0 ? W0 : (z == 1 ? W1 : W2);
  const float* bias = z == 0 ? b0 : (z == 1 ? b1 : b2);
  u16* Out = z == 0 ? O0 : (z == 1 ? O1 : O2);
  // Q pre-scale: (1/sqrt(64)) * log2(e), so attn scores are in log2 units
  const float qs = (z == 0) ? 0.18033688011112042f : 1.0f;
  const int tid = threadIdx.x;
  const int lane = tid & 63, g = lane >> 4, c = lane & 15;
  const int wave = tid >> 6;
  const int wm = wave >> 1, wn = wave & 1;
  const int bm0 = ymt * 128, bn0 = xnt * 128;

  // per-thread staging chunk geometry (invariant over k0): 4 chunks per matrix
  int srow[4], scol[4];
#pragma unroll
  for (int cc = 0; cc < 4; ++cc) {
    const int ci = cc * 256 + tid;          // chunk 0..1023
    srow[cc] = ci >> 3;
    scol[cc] = ((ci & 7) ^ (srow[cc] & 7)) << 3;  // inverse-swizzled source col
  }

  f32x4 acc[4][4];
#pragma unroll
  for (int m = 0; m < 4; ++m)
#pragma unroll
    for (int n = 0; n < 4; ++n) acc[m][n] = (f32x4){0.f, 0.f, 0.f, 0.f};

  u32x4 ar0, ar1, ar2, ar3, br0, br1, br2, br3;
#define GLOAD(k0_) do {                                                        \
    ar0 = *(const u32x4*)(Xb + (size_t)(bm0 + srow[0]) * DMODEL + (k0_) + scol[0]); \
    br0 = *(const u32x4*)(Wm + (size_t)(bn0 + srow[0]) * DMODEL + (k0_) + scol[0]); \
    ar1 = *(const u32x4*)(Xb + (size_t)(bm0 + srow[1]) * DMODEL + (k0_) + scol[1]); \
    br1 = *(const u32x4*)(Wm + (size_t)(bn0 + srow[1]) * DMODEL + (k0_) + scol[1]); \
    ar2 = *(const u32x4*)(Xb + (size_t)(bm0 + srow[2]) * DMODEL + (k0_) + scol[2]); \
    br2 = *(const u32x4*)(Wm + (size_t)(bn0 + srow[2]) * DMODEL + (k0_) + scol[2]); \
    ar3 = *(const u32x4*)(Xb + (size_t)(bm0 + srow[3]) * DMODEL + (k0_) + scol[3]); \
    br3 = *(const u32x4*)(Wm + (size_t)(bn0 + srow[3]) * DMODEL + (k0_) + scol[3]); \
  } while (0)

  GLOAD(0);
  for (int k0 = 0; k0 < DMODEL; k0 += 64) {
    __syncthreads();   // prev step's LDS reads done
    *(u32x4*)((char*)As + (0 * 256 + tid) * 16) = ar0;
    *(u32x4*)((char*)Bs + (0 * 256 + tid) * 16) = br0;
    *(u32x4*)((char*)As + (1 * 256 + tid) * 16) = ar1;
    *(u32x4*)((char*)Bs + (1 * 256 + tid) * 16) = br1;
    *(u32x4*)((char*)As + (2 * 256 + tid) * 16) = ar2;
    *(u32x4*)((char*)Bs + (2 * 256 + tid) * 16) = br2;
    *(u32x4*)((char*)As + (3 * 256 + tid) * 16) = ar3;
    *(u32x4*)((char*)Bs + (3 * 256 + tid) * 16) = br3;
    __syncthreads();   // tile ready
    if (k0 + 64 < DMODEL) GLOAD(k0 + 64);  // hides under compute
#pragma unroll
    for (int ks = 0; ks < 2; ++ks) {
      bf16x8 af[4], bfr[4];
#pragma unroll
      for (int m = 0; m < 4; ++m) {
        const int arow = wm * 64 + m * 16 + c;
        af[m] = *(const bf16x8*)((const char*)As + arow * 128 +
                                 (((ks * 4 + g) ^ (arow & 7)) << 4));
      }
#pragma unroll
      for (int n = 0; n < 4; ++n) {
        const int brow = wn * 64 + n * 16 + c;
        bfr[n] = *(const bf16x8*)((const char*)Bs + brow * 128 +
                                  (((ks * 4 + g) ^ (brow & 7)) << 4));
      }
#pragma unroll
      for (int m = 0; m < 4; ++m)
#pragma unroll
        for (int n = 0; n < 4; ++n)
          acc[m][n] = mfma16(af[m], bfr[n], acc[m][n]);
    }
  }
#undef GLOAD
  if (z < 2) {
    // Q/K: (b,h,s,d) scatter
#pragma unroll
    for (int n = 0; n < 4; ++n) {
      const int coln = bn0 + wn * 64 + n * 16 + c;
      const float bn_ = bias[coln];
      const int h = coln >> 6, d = coln & 63;
#pragma unroll
      for (int m = 0; m < 4; ++m) {
#pragma unroll
        for (int r = 0; r < 4; ++r) {
          const int rowm = bm0 + wm * 64 + m * 16 + g * 4 + r;
          const int b_ = rowm >> 11, s_ = rowm & 2047;
          Out[(((size_t)(b_ * NHEAD + h) * S_LEN + s_) << 6) + d] =
              f2bf((acc[m][n][r] + bn_) * qs);
        }
      }
    }
  } else {
    // V^T: (b,h,d,s) — pack the 4 consecutive-s values into one 8B store
#pragma unroll
    for (int n = 0; n < 4; ++n) {
      const int coln = bn0 + wn * 64 + n * 16 + c;
      const float bn_ = bias[coln];
      const int h = coln >> 6, d = coln & 63;
#pragma unroll
      for (int m = 0; m < 4; ++m) {
        const int row0 = bm0 + wm * 64 + m * 16 + g * 4;
        const int b_ = row0 >> 11, s_ = row0 & 2047;
        u16x4 pk;
#pragma unroll
        for (int r = 0; r < 4; ++r) pk[r] = f2bf(acc[m][n][r] + bn_);
        *(u16x4*)(Out + ((size_t)(b_ * NHEAD + h) * DHEAD + d) * S_LEN + s_) = pk;
      }
    }
  }
}

// ---------------- output projection GEMM (BK=64, swizzled LDS, T14 reg-staging) ----------------
__global__ __launch_bounds__(256) void gemm_out(
    const u16* __restrict__ Ab, const u16* __restrict__ Wm,
    const float* __restrict__ bias, float* __restrict__ Out) {
  __shared__ u16 As[128 * 64];
  __shared__ u16 Bs[128 * 64];
  const int flat = blockIdx.x;
  const int xcd = flat & 7, idx = flat >> 3;   // 64 blocks per XCD
  const int ymt = xcd * 8 + (idx >> 3);        // m-tile 0..63
  const int xnt = idx & 7;                     // n-tile 0..7
  const int tid = threadIdx.x;
  const int lane = tid & 63, g = lane >> 4, c = lane & 15;
  const int wave = tid >> 6;
  const int wm = wave >> 1, wn = wave & 1;
  const int bm0 = ymt * 128, bn0 = xnt * 128;

  int srow[4], scol[4];
#pragma unroll
  for (int cc = 0; cc < 4; ++cc) {
    const int ci = cc * 256 + tid;
    srow[cc] = ci >> 3;
    scol[cc] = ((ci & 7) ^ (srow[cc] & 7)) << 3;
  }

  f32x4 acc[4][4];
#pragma unroll
  for (int m = 0; m < 4; ++m)
#pragma unroll
    for (int n = 0; n < 4; ++n) acc[m][n] = (f32x4){0.f, 0.f, 0.f, 0.f};

  u32x4 ar0, ar1, ar2, ar3, br0, br1, br2, br3;
#define GLOAD(k0_) do {                                                        \
    ar0 = *(const u32x4*)(Ab + (size_t)(bm0 + srow[0]) * DMODEL + (k0_) + scol[0]); \
    br0 = *(const u32x4*)(Wm + (size_t)(bn0 + srow[0]) * DMODEL + (k0_) + scol[0]); \
    ar1 = *(const u32x4*)(Ab + (size_t)(bm0 + srow[1]) * DMODEL + (k0_) + scol[1]); \
    br1 = *(const u32x4*)(Wm + (size_t)(bn0 + srow[1]) * DMODEL + (k0_) + scol[1]); \
    ar2 = *(const u32x4*)(Ab + (size_t)(bm0 + srow[2]) * DMODEL + (k0_) + scol[2]); \
    br2 = *(const u32x4*)(Wm + (size_t)(bn0 + srow[2]) * DMODEL + (k0_) + scol[2]); \
    ar3 = *(const u32x4*)(Ab + (size_t)(bm0 + srow[3]) * DMODEL + (k0_) + scol[3]); \
    br3 = *(const u32x4*)(Wm + (size_t)(bn0 + srow[3]) * DMODEL + (k0_) + scol[3]); \
  } while (0)

  GLOAD(0);
  for (int k0 = 0; k0 < DMODEL; k0 += 64) {
    __syncthreads();
    *(u32x4*)((char*)As + (0 * 256 + tid) * 16) = ar0;
    *(u32x4*)((char*)Bs + (0 * 256 + tid) * 16) = br0;
    *(u32x4*)((char*)As + (1 * 256 + tid) * 16) = ar1;
    *(u32x4*)((char*)Bs + (1 * 256 + tid) * 16) = br1;
    *(u32x4*)((char*)As + (2 * 256 + tid) * 16) = ar2;
    *(u32x4*)((char*)Bs + (2 * 256 + tid) * 16) = br2;
    *(u32x4*)((char*)As + (3 * 256 + tid) * 16) = ar3;
    *(u32x4*)((char*)Bs + (3 * 256 + tid) * 16) = br3;
    __syncthreads();
    if (k0 + 64 < DMODEL) GLOAD(k0 + 64);
#pragma unroll
    for (int ks = 0; ks < 2; ++ks) {
      bf16x8 af[4], bfr[4];
#pragma unroll
      for (int m = 0; m < 4; ++m) {
        const int arow = wm * 64 + m * 16 + c;
        af[m] = *(const bf16x8*)((const char*)As + arow * 128 +
                                 (((ks * 4 + g) ^ (arow & 7)) << 4));
      }
#pragma unroll
      for (int n = 0; n < 4; ++n) {
        const int brow = wn * 64 + n * 16 + c;
        bfr[n] = *(const bf16x8*)((const char*)Bs + brow * 128 +
                                  (((ks * 4 + g) ^ (brow & 7)) << 4));
      }
#pragma unroll
      for (int m = 0; m < 4; ++m)
#pragma unroll
        for (int n = 0; n < 4; ++n)
          acc[m][n] = mfma16(af[m], bfr[n], acc[m][n]);
    }
  }
#undef GLOAD
#pragma unroll
  for (int n = 0; n < 4; ++n) {
    const int coln = bn0 + wn * 64 + n * 16 + c;
    const float bn_ = bias[coln];
#pragma unroll
    for (int m = 0; m < 4; ++m) {
#pragma unroll
      for (int r = 0; r < 4; ++r) {
        const int rowm = bm0 + wm * 64 + m * 16 + g * 4 + r;
        Out[(size_t)rowm * DMODEL + coln] = acc[m][n][r] + bn_;
      }
    }
  }
}

// ---------------- causal flash attention (T14 reg-staging + l-from-MFMA) ----------------
// One 64-row q-tile per block (2048 blocks): xcd=flat&7, idx=flat>>3,
// qt=31-(idx>>3), bh=xcd*8+(idx&7). Staging via global->reg + late ds_write (T14).
// l accumulated by MFMA with a ones A-fragment (every output row = sum_kv P),
// replacing 16 VALU adds + 2 shfl per step. Softmax in-register (log2 units),
// defer-rescale (T13, THR=8); P -> bf16 via v_cvt_pk; PV via wave-local Pl buffer.
__global__ __launch_bounds__(256) void attn_fwd(const u16* __restrict__ Qb,
                                                const u16* __restrict__ Kb,
                                                const u16* __restrict__ VTb,
                                                u16* __restrict__ AOb) {
  __shared__ u16 Kt[64 * 64];       // K tile [kv][d], swizzled chunks
  __shared__ u16 Vt[64 * 64];       // V^T tile [d][kv], swizzled chunks
  __shared__ unsigned Pl[4][16 * 36];  // per-wave P^T: row q=c (stride 36 u32 = 144B)
  const int tid = threadIdx.x;
  const int w = tid >> 6, lane = tid & 63, g = lane >> 4, c = lane & 15;
  const int flat = blockIdx.x;
  const int xcd = flat & 7, idx = flat >> 3;      // 256 blocks per XCD
  const int qt = 31 - (idx >> 3);                 // heavy tiles first
  const int bh = xcd * 8 + (idx & 7);             // 8 heads per XCD
  const size_t base = (size_t)bh * (S_LEN * DHEAD);  // same stride for K and VT
  const int b_ = bh >> 4, h = bh & 15;
  const int ci0 = w * 64 + lane;    // staging chunk index

  // per-thread staging chunk geometry (invariant over kt)
  const int row0_ = ci0 >> 3,            colg0 = (ci0 & 7) ^ (row0_ & 7);
  const int row1_ = (256 + ci0) >> 3,    colg1 = ((256 + ci0) & 7) ^ (row1_ & 7);

  const int qb = qt * 64;
  const int q = qb + w * 16 + c;   // this lane's q-row
  const bf16x8 qf0 = *(const bf16x8*)(Qb + base + (size_t)q * 64 + g * 8);
  const bf16x8 qf1 = *(const bf16x8*)(Qb + base + (size_t)q * 64 + 32 + g * 8);

  bf16x8 ones;
#pragma unroll
  for (int j = 0; j < 8; ++j) ones[j] = (short)0x3F80;  // bf16 1.0

  f32x4 oacc[4];
  f32x4 lacc = (f32x4){0.f, 0.f, 0.f, 0.f};
#pragma unroll
  for (int dt = 0; dt < 4; ++dt) oacc[dt] = (f32x4){0.f, 0.f, 0.f, 0.f};
  float m = -30000.f;

  u32x4 kreg0, kreg1, vreg0, vreg1;  // in-flight staging tile (64B/thread)
#define STAGE_LOAD(kt_) do {                                                  \
    const int kv0_ = (kt_) * 64;                                              \
    kreg0 = *(const u32x4*)(Kb + base + (size_t)(kv0_ + row0_) * 64 + colg0 * 8); \
    vreg0 = *(const u32x4*)(VTb + base + (size_t)row0_ * S_LEN + kv0_ + colg0 * 8); \
    kreg1 = *(const u32x4*)(Kb + base + (size_t)(kv0_ + row1_) * 64 + colg1 * 8); \
    vreg1 = *(const u32x4*)(VTb + base + (size_t)row1_ * S_LEN + kv0_ + colg1 * 8); \
  } while (0)

  const int nt = qt + 1;
  STAGE_LOAD(0);
  for (int kt = 0; kt < nt; ++kt) {
    const int kv0 = kt * 64;
    __syncthreads();  // prev tile's LDS reads done before overwrite
    // write staged regs -> LDS (compiler inserts vmcnt before first write)
    *(u32x4*)((char*)Kt + ci0 * 16) = kreg0;
    *(u32x4*)((char*)Vt + ci0 * 16) = vreg0;
    *(u32x4*)((char*)Kt + (256 + ci0) * 16) = kreg1;
    *(u32x4*)((char*)Vt + (256 + ci0) * 16) = vreg1;
    __syncthreads();  // tile ready
    if (kt + 1 < nt) STAGE_LOAD(kt + 1);  // issue next tile; hides under compute

    // S^T = K Q^T from swizzled LDS: s[t][r] = S[kv=kv0+16t+4g+r][q] (log2 units)
    f32x4 s[4];
#pragma unroll
    for (int t = 0; t < 4; ++t) {
      const int krow = t * 16 + c;
      const char* kbase = (const char*)Kt + krow * 128;
      bf16x8 kf0 = *(const bf16x8*)(kbase + ((g ^ (krow & 7)) * 16));
      bf16x8 kf1 = *(const bf16x8*)(kbase + (((4 + g) ^ (krow & 7)) * 16));
      f32x4 zacc = (f32x4){0.f, 0.f, 0.f, 0.f};
      zacc = mfma16(kf0, qf0, zacc);
      zacc = mfma16(kf1, qf1, zacc);
      s[t] = zacc;
    }
    if (kt == nt - 1) {  // diagonal tile only: causal mask
#pragma unroll
      for (int t = 0; t < 4; ++t)
#pragma unroll
        for (int r = 0; r < 4; ++r)
          if (kv0 + t * 16 + 4 * g + r > q) s[t][r] = -30000.f;
    }
    // row max via max3 tree (16 values) + 2-step cross-g reduce
    const float a0 = fmaxf(fmaxf(s[0][0], s[0][1]), s[0][2]);
    const float a1 = fmaxf(fmaxf(s[0][3], s[1][0]), s[1][1]);
    const float a2 = fmaxf(fmaxf(s[1][2], s[1][3]), s[2][0]);
    const float a3 = fmaxf(fmaxf(s[2][1], s[2][2]), s[2][3]);
    const float a4 = fmaxf(fmaxf(s[3][0], s[3][1]), s[3][2]);
    float pm = fmaxf(fmaxf(fmaxf(a0, a1), a2), fmaxf(fmaxf(a3, a4), s[3][3]));
    pm = fmaxf(pm, __shfl_xor(pm, 16));
    pm = fmaxf(pm, __shfl_xor(pm, 32));
    // defer-rescale (T13): only rescale when some row grew by > 2^8
    if (__any(pm > m + 8.0f)) {
      const float mn = fmaxf(m, pm);
      const float sc = exp2v(m - mn);
      lacc *= sc;
#pragma unroll
      for (int dt = 0; dt < 4; ++dt) oacc[dt] *= sc;
      m = mn;
    }
#pragma unroll
    for (int t = 0; t < 4; ++t) {
      const float p0 = exp2v(s[t][0] - m), p1 = exp2v(s[t][1] - m);
      const float p2 = exp2v(s[t][2] - m), p3 = exp2v(s[t][3] - m);
      // P^T[q=c][kv = 16t+4g+0..3]: two v_cvt_pk_bf16_f32, one 8B store
      u32x2 pk2;
      pk2[0] = pkbf2(p0, p1);
      pk2[1] = pkbf2(p2, p3);
      *(u32x2*)&Pl[w][c * 36 + t * 8 + g * 2] = pk2;
    }

    // O^T += V^T P^T ; l += ones^T P^T (MFMA, ones A-frag: every row = sum_kv P)
#pragma unroll
    for (int kk = 0; kk < 2; ++kk) {
      const bf16x8 pb = *(const bf16x8*)&Pl[w][c * 36 + kk * 16 + g * 4];
      lacc = mfma16(ones, pb, lacc);
#pragma unroll
      for (int dt = 0; dt < 4; ++dt) {
        const int vrow = dt * 16 + c;
        const bf16x8 vf = *(const bf16x8*)((const char*)Vt + vrow * 128 +
                                           (((kk * 4 + g) ^ (vrow & 7)) * 16));
        oacc[dt] = mfma16(vf, pb, oacc[dt]);
      }
    }
  }
#undef STAGE_LOAD
  // epilogue: lane owns O[q][d = dt*16 + 4g + 0..3] -> 8B packed stores
  const float inv = 1.0f / lacc[0];
  const size_t rowbase = ((size_t)(b_ * S_LEN + q) * DMODEL) + h * 64;
#pragma unroll
  for (int dt = 0; dt < 4; ++dt) {
    u16x4 pk4;
#pragma unroll
    for (int r = 0; r < 4; ++r) pk4[r] = f2bf(oacc[dt][r] * inv);
    *(u16x4*)(AOb + rowbase + dt * 16 + 4 * g) = pk4;
  }
}

extern "C" void kernel_launch(void* const* d_in, const int* in_sizes, int n_in,
                              void* d_out, int out_size, void* d_ws, size_t ws_size,
                              hipStream_t stream) {
  const float* x  = (const float*)d_in[0];
  const float* Wq = (const float*)d_in[1];
  const float* bq = (const float*)d_in[2];
  const float* Wk = (const float*)d_in[3];
  const float* bk = (const float*)d_in[4];
  const float* Wv = (const float*)d_in[5];
  const float* bv = (const float*)d_in[6];
  const float* Wo = (const float*)d_in[7];
  const float* bo = (const float*)d_in[8];
  float* out = (float*)d_out;
  char* ws = (char*)d_ws;

  const size_t MB = 1024 * 1024;
  u16* xb  = (u16*)(ws);              // 16 MB: x bf16 [8192][1024]
  u16* Wqb = (u16*)(ws + 16 * MB);    // 2 MB each
  u16* Wkb = (u16*)(ws + 18 * MB);
  u16* Wvb = (u16*)(ws + 20 * MB);
  u16* Wob = (u16*)(ws + 22 * MB);
  u16* Qb  = (u16*)(ws + 24 * MB);    // 16 MB (b,h,s,d), pre-scaled (log2 units)
  u16* Kb  = (u16*)(ws + 40 * MB);    // 16 MB (b,h,s,d)
  u16* VTb = (u16*)(ws + 56 * MB);    // 16 MB (b,h,d,s)
  u16* AOb = (u16*)(ws + 72 * MB);    // 16 MB (b,s,h*d)

  castall<<<6144, 256, 0, stream>>>(x, Wq, Wk, Wv, Wo, xb, Wqb, Wkb, Wvb, Wob);

  gemm_qkv<<<1536, 256, 0, stream>>>(
      xb, Wqb, Wkb, Wvb, bq, bk, bv, Qb, Kb, VTb);

  attn_fwd<<<2048, 256, 0, stream>>>(Qb, Kb, VTb, AOb);

  gemm_out<<<512, 256, 0, stream>>>(AOb, Wob, bo, out);
}

// Round 21
// 164.087 us; speedup vs baseline: 1.1672x; 1.0245x over previous
//
#include <hip/hip_runtime.h>
#include <hip/hip_bf16.h>
#include <math.h>

#define S_LEN 2048
#define DMODEL 1024
#define NHEAD 16
#define DHEAD 64
#define BATCH 4
#define MROWS (BATCH * S_LEN)  // 8192

typedef unsigned short u16;
typedef __attribute__((ext_vector_type(4))) unsigned short u16x4;
typedef __attribute__((ext_vector_type(8))) unsigned short u16x8;
typedef __attribute__((ext_vector_type(2))) unsigned u32x2;
typedef __attribute__((ext_vector_type(4))) unsigned u32x4;
typedef __attribute__((ext_vector_type(8))) short bf16x8;
typedef __attribute__((ext_vector_type(4))) float f32x4;

__device__ __forceinline__ u16 f2bf(float f) {
  unsigned u = __float_as_uint(f);
  u += 0x7fff + ((u >> 16) & 1);  // round-to-nearest-even
  return (u16)(u >> 16);
}

__device__ __forceinline__ unsigned pkbf2(float lo, float hi) {
  // single v_cvt_pk_bf16_f32: lo -> bits[15:0], hi -> bits[31:16]
  __hip_bfloat162 h = __float22bfloat162_rn(float2{lo, hi});
  unsigned r;
  __builtin_memcpy(&r, &h, 4);
  return r;
}

__device__ __forceinline__ float exp2v(float x) {  // raw v_exp_f32 (base-2)
  float r;
  asm("v_exp_f32 %0, %1" : "=v"(r) : "v"(x));
  return r;
}

__device__ __forceinline__ f32x4 mfma16(bf16x8 a, bf16x8 b, f32x4 c) {
  return __builtin_amdgcn_mfma_f32_16x16x32_bf16(a, b, c, 0, 0, 0);
}

// ---------------- fused cast fp32 -> bf16 (x + 4 weight matrices, one launch) ----------------
// blocks 0..4095 -> x (8192x1024); then 512-block ranges for Wq, Wk, Wv, Wo.
__global__ __launch_bounds__(256) void castall(
    const float* __restrict__ x,
    const float* __restrict__ w0, const float* __restrict__ w1,
    const float* __restrict__ w2, const float* __restrict__ w3,
    u16* __restrict__ ox,
    u16* __restrict__ o0, u16* __restrict__ o1,
    u16* __restrict__ o2, u16* __restrict__ o3) {
  const int blk = blockIdx.x;
  const float* in;
  u16* out;
  int base;
  if (blk < 4096)      { in = x;  out = ox; base = blk; }
  else if (blk < 4608) { in = w0; out = o0; base = blk - 4096; }
  else if (blk < 5120) { in = w1; out = o1; base = blk - 4608; }
  else if (blk < 5632) { in = w2; out = o2; base = blk - 5120; }
  else                 { in = w3; out = o3; base = blk - 5632; }
  const int i = (base * 256 + threadIdx.x) * 8;
  f32x4 v0 = *(const f32x4*)(in + i);
  f32x4 v1 = *(const f32x4*)(in + i + 4);
  u16x8 o;
#pragma unroll
  for (int j = 0; j < 4; ++j) { o[j] = f2bf(v0[j]); o[4 + j] = f2bf(v1[j]); }
  *(u16x8*)(out + i) = o;
}

// ---------------- QKV projection GEMM (BK=64, swizzled LDS, T14 reg-staging) ----------------
// Within each XCD: msub = idx&7 (fast), nz = idx>>3 (slow) -> any 64-block
// concurrent window = 8 W panels (2MB) + 8 X panels (2MB) = 4MB = L2 size;
// X stays L2-resident across the whole nz sweep (T1 L2-retention order).
__global__ __launch_bounds__(256) void gemm_qkv(
    const u16* __restrict__ Xb,
    const u16* __restrict__ W0, const u16* __restrict__ W1, const u16* __restrict__ W2,
    const float* __restrict__ b0, const float* __restrict__ b1, const float* __restrict__ b2,
    u16* __restrict__ O0, u16* __restrict__ O1, u16* __restrict__ O2) {
  __shared__ u16 As[128 * 64];
  __shared__ u16 Bs[128 * 64];
  const int flat = blockIdx.x;
  const int xcd = flat & 7, idx = flat >> 3;   // 192 blocks per XCD
  const int msub = idx & 7;                    // m fast
  const int nz = idx >> 3;                     // (n,z) slow: 0..23
  const int ymt = xcd * 8 + msub;              // m-tile 0..63
  const int xnt = nz & 7;                      // n-tile 0..7
  const int z = nz >> 3;                       // 0..2 (Q/K/V)
  const u16* Wm = z == 0 ? W0 : (z == 1 ? W1 : W2);
  const float* bias = z == 0 ? b0 : (z == 1 ? b1 : b2);
  u16* Out = z == 0 ? O0 : (z == 1 ? O1 : O2);
  // Q pre-scale: (1/sqrt(64)) * log2(e), so attn scores are in log2 units
  const float qs = (z == 0) ? 0.18033688011112042f : 1.0f;
  const int tid = threadIdx.x;
  const int lane = tid & 63, g = lane >> 4, c = lane & 15;
  const int wave = tid >> 6;
  const int wm = wave >> 1, wn = wave & 1;
  const int bm0 = ymt * 128, bn0 = xnt * 128;

  // per-thread staging chunk geometry (invariant over k0): 4 chunks per matrix
  int srow[4], scol[4];
#pragma unroll
  for (int cc = 0; cc < 4; ++cc) {
    const int ci = cc * 256 + tid;          // chunk 0..1023
    srow[cc] = ci >> 3;
    scol[cc] = ((ci & 7) ^ (srow[cc] & 7)) << 3;  // inverse-swizzled source col
  }

  f32x4 acc[4][4];
#pragma unroll
  for (int m = 0; m < 4; ++m)
#pragma unroll
    for (int n = 0; n < 4; ++n) acc[m][n] = (f32x4){0.f, 0.f, 0.f, 0.f};

  u32x4 ar0, ar1, ar2, ar3, br0, br1, br2, br3;
#define GLOAD(k0_) do {                                                        \
    ar0 = *(const u32x4*)(Xb + (size_t)(bm0 + srow[0]) * DMODEL + (k0_) + scol[0]); \
    br0 = *(const u32x4*)(Wm + (size_t)(bn0 + srow[0]) * DMODEL + (k0_) + scol[0]); \
    ar1 = *(const u32x4*)(Xb + (size_t)(bm0 + srow[1]) * DMODEL + (k0_) + scol[1]); \
    br1 = *(const u32x4*)(Wm + (size_t)(bn0 + srow[1]) * DMODEL + (k0_) + scol[1]); \
    ar2 = *(const u32x4*)(Xb + (size_t)(bm0 + srow[2]) * DMODEL + (k0_) + scol[2]); \
    br2 = *(const u32x4*)(Wm + (size_t)(bn0 + srow[2]) * DMODEL + (k0_) + scol[2]); \
    ar3 = *(const u32x4*)(Xb + (size_t)(bm0 + srow[3]) * DMODEL + (k0_) + scol[3]); \
    br3 = *(const u32x4*)(Wm + (size_t)(bn0 + srow[3]) * DMODEL + (k0_) + scol[3]); \
  } while (0)

  GLOAD(0);
  for (int k0 = 0; k0 < DMODEL; k0 += 64) {
    __syncthreads();   // prev step's LDS reads done
    *(u32x4*)((char*)As + (0 * 256 + tid) * 16) = ar0;
    *(u32x4*)((char*)Bs + (0 * 256 + tid) * 16) = br0;
    *(u32x4*)((char*)As + (1 * 256 + tid) * 16) = ar1;
    *(u32x4*)((char*)Bs + (1 * 256 + tid) * 16) = br1;
    *(u32x4*)((char*)As + (2 * 256 + tid) * 16) = ar2;
    *(u32x4*)((char*)Bs + (2 * 256 + tid) * 16) = br2;
    *(u32x4*)((char*)As + (3 * 256 + tid) * 16) = ar3;
    *(u32x4*)((char*)Bs + (3 * 256 + tid) * 16) = br3;
    __syncthreads();   // tile ready
    if (k0 + 64 < DMODEL) GLOAD(k0 + 64);  // hides under compute
#pragma unroll
    for (int ks = 0; ks < 2; ++ks) {
      bf16x8 af[4], bfr[4];
#pragma unroll
      for (int m = 0; m < 4; ++m) {
        const int arow = wm * 64 + m * 16 + c;
        af[m] = *(const bf16x8*)((const char*)As + arow * 128 +
                                 (((ks * 4 + g) ^ (arow & 7)) << 4));
      }
#pragma unroll
      for (int n = 0; n < 4; ++n) {
        const int brow = wn * 64 + n * 16 + c;
        bfr[n] = *(const bf16x8*)((const char*)Bs + brow * 128 +
                                  (((ks * 4 + g) ^ (brow & 7)) << 4));
      }
#pragma unroll
      for (int m = 0; m < 4; ++m)
#pragma unroll
        for (int n = 0; n < 4; ++n)
          acc[m][n] = mfma16(af[m], bfr[n], acc[m][n]);
    }
  }
#undef GLOAD
  if (z < 2) {
    // Q/K: (b,h,s,d) scatter
#pragma unroll
    for (int n = 0; n < 4; ++n) {
      const int coln = bn0 + wn * 64 + n * 16 + c;
      const float bn_ = bias[coln];
      const int h = coln >> 6, d = coln & 63;
#pragma unroll
      for (int m = 0; m < 4; ++m) {
#pragma unroll
        for (int r = 0; r < 4; ++r) {
          const int rowm = bm0 + wm * 64 + m * 16 + g * 4 + r;
          const int b_ = rowm >> 11, s_ = rowm & 2047;
          Out[(((size_t)(b_ * NHEAD + h) * S_LEN + s_) << 6) + d] =
              f2bf((acc[m][n][r] + bn_) * qs);
        }
      }
    }
  } else {
    // V^T: (b,h,d,s) — pack the 4 consecutive-s values into one 8B store
#pragma unroll
    for (int n = 0; n < 4; ++n) {
      const int coln = bn0 + wn * 64 + n * 16 + c;
      const float bn_ = bias[coln];
      const int h = coln >> 6, d = coln & 63;
#pragma unroll
      for (int m = 0; m < 4; ++m) {
        const int row0 = bm0 + wm * 64 + m * 16 + g * 4;
        const int b_ = row0 >> 11, s_ = row0 & 2047;
        u16x4 pk;
#pragma unroll
        for (int r = 0; r < 4; ++r) pk[r] = f2bf(acc[m][n][r] + bn_);
        *(u16x4*)(Out + ((size_t)(b_ * NHEAD + h) * DHEAD + d) * S_LEN + s_) = pk;
      }
    }
  }
}

// ---------------- output projection GEMM (BK=64, swizzled LDS, T14 reg-staging) ----------------
__global__ __launch_bounds__(256) void gemm_out(
    const u16* __restrict__ Ab, const u16* __restrict__ Wm,
    const float* __restrict__ bias, float* __restrict__ Out) {
  __shared__ u16 As[128 * 64];
  __shared__ u16 Bs[128 * 64];
  const int flat = blockIdx.x;
  const int xcd = flat & 7, idx = flat >> 3;   // 64 blocks per XCD
  const int ymt = xcd * 8 + (idx & 7);         // m fast
  const int xnt = idx >> 3;                    // n slow
  const int tid = threadIdx.x;
  const int lane = tid & 63, g = lane >> 4, c = lane & 15;
  const int wave = tid >> 6;
  const int wm = wave >> 1, wn = wave & 1;
  const int bm0 = ymt * 128, bn0 = xnt * 128;

  int srow[4], scol[4];
#pragma unroll
  for (int cc = 0; cc < 4; ++cc) {
    const int ci = cc * 256 + tid;
    srow[cc] = ci >> 3;
    scol[cc] = ((ci & 7) ^ (srow[cc] & 7)) << 3;
  }

  f32x4 acc[4][4];
#pragma unroll
  for (int m = 0; m < 4; ++m)
#pragma unroll
    for (int n = 0; n < 4; ++n) acc[m][n] = (f32x4){0.f, 0.f, 0.f, 0.f};

  u32x4 ar0, ar1, ar2, ar3, br0, br1, br2, br3;
#define GLOAD(k0_) do {                                                        \
    ar0 = *(const u32x4*)(Ab + (size_t)(bm0 + srow[0]) * DMODEL + (k0_) + scol[0]); \
    br0 = *(const u32x4*)(Wm + (size_t)(bn0 + srow[0]) * DMODEL + (k0_) + scol[0]); \
    ar1 = *(const u32x4*)(Ab + (size_t)(bm0 + srow[1]) * DMODEL + (k0_) + scol[1]); \
    br1 = *(const u32x4*)(Wm + (size_t)(bn0 + srow[1]) * DMODEL + (k0_) + scol[1]); \
    ar2 = *(const u32x4*)(Ab + (size_t)(bm0 + srow[2]) * DMODEL + (k0_) + scol[2]); \
    br2 = *(const u32x4*)(Wm + (size_t)(bn0 + srow[2]) * DMODEL + (k0_) + scol[2]); \
    ar3 = *(const u32x4*)(Ab + (size_t)(bm0 + srow[3]) * DMODEL + (k0_) + scol[3]); \
    br3 = *(const u32x4*)(Wm + (size_t)(bn0 + srow[3]) * DMODEL + (k0_) + scol[3]); \
  } while (0)

  GLOAD(0);
  for (int k0 = 0; k0 < DMODEL; k0 += 64) {
    __syncthreads();
    *(u32x4*)((char*)As + (0 * 256 + tid) * 16) = ar0;
    *(u32x4*)((char*)Bs + (0 * 256 + tid) * 16) = br0;
    *(u32x4*)((char*)As + (1 * 256 + tid) * 16) = ar1;
    *(u32x4*)((char*)Bs + (1 * 256 + tid) * 16) = br1;
    *(u32x4*)((char*)As + (2 * 256 + tid) * 16) = ar2;
    *(u32x4*)((char*)Bs + (2 * 256 + tid) * 16) = br2;
    *(u32x4*)((char*)As + (3 * 256 + tid) * 16) = ar3;
    *(u32x4*)((char*)Bs + (3 * 256 + tid) * 16) = br3;
    __syncthreads();
    if (k0 + 64 < DMODEL) GLOAD(k0 + 64);
#pragma unroll
    for (int ks = 0; ks < 2; ++ks) {
      bf16x8 af[4], bfr[4];
#pragma unroll
      for (int m = 0; m < 4; ++m) {
        const int arow = wm * 64 + m * 16 + c;
        af[m] = *(const bf16x8*)((const char*)As + arow * 128 +
                                 (((ks * 4 + g) ^ (arow & 7)) << 4));
      }
#pragma unroll
      for (int n = 0; n < 4; ++n) {
        const int brow = wn * 64 + n * 16 + c;
        bfr[n] = *(const bf16x8*)((const char*)Bs + brow * 128 +
                                  (((ks * 4 + g) ^ (brow & 7)) << 4));
      }
#pragma unroll
      for (int m = 0; m < 4; ++m)
#pragma unroll
        for (int n = 0; n < 4; ++n)
          acc[m][n] = mfma16(af[m], bfr[n], acc[m][n]);
    }
  }
#undef GLOAD
#pragma unroll
  for (int n = 0; n < 4; ++n) {
    const int coln = bn0 + wn * 64 + n * 16 + c;
    const float bn_ = bias[coln];
#pragma unroll
    for (int m = 0; m < 4; ++m) {
#pragma unroll
      for (int r = 0; r < 4; ++r) {
        const int rowm = bm0 + wm * 64 + m * 16 + g * 4 + r;
        Out[(size_t)rowm * DMODEL + coln] = acc[m][n][r] + bn_;
      }
    }
  }
}

// ---------------- causal flash attention (T14 reg-staging + l-from-MFMA) ----------------
// One 64-row q-tile per block (2048 blocks): xcd=flat&7, idx=flat>>3,
// qt=31-(idx>>3), bh=xcd*8+(idx&7). Staging via global->reg + late ds_write (T14).
// l accumulated by MFMA with a ones A-fragment (every output row = sum_kv P),
// replacing 16 VALU adds + 2 shfl per step. Softmax in-register (log2 units),
// defer-rescale (T13, THR=8); P -> bf16 via v_cvt_pk; PV via wave-local Pl buffer.
__global__ __launch_bounds__(256) void attn_fwd(const u16* __restrict__ Qb,
                                                const u16* __restrict__ Kb,
                                                const u16* __restrict__ VTb,
                                                u16* __restrict__ AOb) {
  __shared__ u16 Kt[64 * 64];       // K tile [kv][d], swizzled chunks
  __shared__ u16 Vt[64 * 64];       // V^T tile [d][kv], swizzled chunks
  __shared__ unsigned Pl[4][16 * 36];  // per-wave P^T: row q=c (stride 36 u32 = 144B)
  const int tid = threadIdx.x;
  const int w = tid >> 6, lane = tid & 63, g = lane >> 4, c = lane & 15;
  const int flat = blockIdx.x;
  const int xcd = flat & 7, idx = flat >> 3;      // 256 blocks per XCD
  const int qt = 31 - (idx >> 3);                 // heavy tiles first
  const int bh = xcd * 8 + (idx & 7);             // 8 heads per XCD
  const size_t base = (size_t)bh * (S_LEN * DHEAD);  // same stride for K and VT
  const int b_ = bh >> 4, h = bh & 15;
  const int ci0 = w * 64 + lane;    // staging chunk index

  // per-thread staging chunk geometry (invariant over kt)
  const int row0_ = ci0 >> 3,            colg0 = (ci0 & 7) ^ (row0_ & 7);
  const int row1_ = (256 + ci0) >> 3,    colg1 = ((256 + ci0) & 7) ^ (row1_ & 7);

  const int qb = qt * 64;
  const int q = qb + w * 16 + c;   // this lane's q-row
  const bf16x8 qf0 = *(const bf16x8*)(Qb + base + (size_t)q * 64 + g * 8);
  const bf16x8 qf1 = *(const bf16x8*)(Qb + base + (size_t)q * 64 + 32 + g * 8);

  bf16x8 ones;
#pragma unroll
  for (int j = 0; j < 8; ++j) ones[j] = (short)0x3F80;  // bf16 1.0

  f32x4 oacc[4];
  f32x4 lacc = (f32x4){0.f, 0.f, 0.f, 0.f};
#pragma unroll
  for (int dt = 0; dt < 4; ++dt) oacc[dt] = (f32x4){0.f, 0.f, 0.f, 0.f};
  float m = -30000.f;

  u32x4 kreg0, kreg1, vreg0, vreg1;  // in-flight staging tile (64B/thread)
#define STAGE_LOAD(kt_) do {                                                  \
    const int kv0_ = (kt_) * 64;                                              \
    kreg0 = *(const u32x4*)(Kb + base + (size_t)(kv0_ + row0_) * 64 + colg0 * 8); \
    vreg0 = *(const u32x4*)(VTb + base + (size_t)row0_ * S_LEN + kv0_ + colg0 * 8); \
    kreg1 = *(const u32x4*)(Kb + base + (size_t)(kv0_ + row1_) * 64 + colg1 * 8); \
    vreg1 = *(const u32x4*)(VTb + base + (size_t)row1_ * S_LEN + kv0_ + colg1 * 8); \
  } while (0)

  const int nt = qt + 1;
  STAGE_LOAD(0);
  for (int kt = 0; kt < nt; ++kt) {
    const int kv0 = kt * 64;
    __syncthreads();  // prev tile's LDS reads done before overwrite
    // write staged regs -> LDS (compiler inserts vmcnt before first write)
    *(u32x4*)((char*)Kt + ci0 * 16) = kreg0;
    *(u32x4*)((char*)Vt + ci0 * 16) = vreg0;
    *(u32x4*)((char*)Kt + (256 + ci0) * 16) = kreg1;
    *(u32x4*)((char*)Vt + (256 + ci0) * 16) = vreg1;
    __syncthreads();  // tile ready
    if (kt + 1 < nt) STAGE_LOAD(kt + 1);  // issue next tile; hides under compute

    // S^T = K Q^T from swizzled LDS: s[t][r] = S[kv=kv0+16t+4g+r][q] (log2 units)
    f32x4 s[4];
#pragma unroll
    for (int t = 0; t < 4; ++t) {
      const int krow = t * 16 + c;
      const char* kbase = (const char*)Kt + krow * 128;
      bf16x8 kf0 = *(const bf16x8*)(kbase + ((g ^ (krow & 7)) * 16));
      bf16x8 kf1 = *(const bf16x8*)(kbase + (((4 + g) ^ (krow & 7)) * 16));
      f32x4 zacc = (f32x4){0.f, 0.f, 0.f, 0.f};
      zacc = mfma16(kf0, qf0, zacc);
      zacc = mfma16(kf1, qf1, zacc);
      s[t] = zacc;
    }
    if (kt == nt - 1) {  // diagonal tile only: causal mask
#pragma unroll
      for (int t = 0; t < 4; ++t)
#pragma unroll
        for (int r = 0; r < 4; ++r)
          if (kv0 + t * 16 + 4 * g + r > q) s[t][r] = -30000.f;
    }
    // row max via max3 tree (16 values) + 2-step cross-g reduce
    const float a0 = fmaxf(fmaxf(s[0][0], s[0][1]), s[0][2]);
    const float a1 = fmaxf(fmaxf(s[0][3], s[1][0]), s[1][1]);
    const float a2 = fmaxf(fmaxf(s[1][2], s[1][3]), s[2][0]);
    const float a3 = fmaxf(fmaxf(s[2][1], s[2][2]), s[2][3]);
    const float a4 = fmaxf(fmaxf(s[3][0], s[3][1]), s[3][2]);
    float pm = fmaxf(fmaxf(fmaxf(a0, a1), a2), fmaxf(fmaxf(a3, a4), s[3][3]));
    pm = fmaxf(pm, __shfl_xor(pm, 16));
    pm = fmaxf(pm, __shfl_xor(pm, 32));
    // defer-rescale (T13): only rescale when some row grew by > 2^8
    if (__any(pm > m + 8.0f)) {
      const float mn = fmaxf(m, pm);
      const float sc = exp2v(m - mn);
      lacc *= sc;
#pragma unroll
      for (int dt = 0; dt < 4; ++dt) oacc[dt] *= sc;
      m = mn;
    }
#pragma unroll
    for (int t = 0; t < 4; ++t) {
      const float p0 = exp2v(s[t][0] - m), p1 = exp2v(s[t][1] - m);
      const float p2 = exp2v(s[t][2] - m), p3 = exp2v(s[t][3] - m);
      // P^T[q=c][kv = 16t+4g+0..3]: two v_cvt_pk_bf16_f32, one 8B store
      u32x2 pk2;
      pk2[0] = pkbf2(p0, p1);
      pk2[1] = pkbf2(p2, p3);
      *(u32x2*)&Pl[w][c * 36 + t * 8 + g * 2] = pk2;
    }

    // O^T += V^T P^T ; l += ones^T P^T (MFMA, ones A-frag: every row = sum_kv P)
#pragma unroll
    for (int kk = 0; kk < 2; ++kk) {
      const bf16x8 pb = *(const bf16x8*)&Pl[w][c * 36 + kk * 16 + g * 4];
      lacc = mfma16(ones, pb, lacc);
#pragma unroll
      for (int dt = 0; dt < 4; ++dt) {
        const int vrow = dt * 16 + c;
        const bf16x8 vf = *(const bf16x8*)((const char*)Vt + vrow * 128 +
                                           (((kk * 4 + g) ^ (vrow & 7)) * 16));
        oacc[dt] = mfma16(vf, pb, oacc[dt]);
      }
    }
  }
#undef STAGE_LOAD
  // epilogue: lane owns O[q][d = dt*16 + 4g + 0..3] -> 8B packed stores
  const float inv = 1.0f / lacc[0];
  const size_t rowbase = ((size_t)(b_ * S_LEN + q) * DMODEL) + h * 64;
#pragma unroll
  for (int dt = 0; dt < 4; ++dt) {
    u16x4 pk4;
#pragma unroll
    for (int r = 0; r < 4; ++r) pk4[r] = f2bf(oacc[dt][r] * inv);
    *(u16x4*)(AOb + rowbase + dt * 16 + 4 * g) = pk4;
  }
}

extern "C" void kernel_launch(void* const* d_in, const int* in_sizes, int n_in,
                              void* d_out, int out_size, void* d_ws, size_t ws_size,
                              hipStream_t stream) {
  const float* x  = (const float*)d_in[0];
  const float* Wq = (const float*)d_in[1];
  const float* bq = (const float*)d_in[2];
  const float* Wk = (const float*)d_in[3];
  const float* bk = (const float*)d_in[4];
  const float* Wv = (const float*)d_in[5];
  const float* bv = (const float*)d_in[6];
  const float* Wo = (const float*)d_in[7];
  const float* bo = (const float*)d_in[8];
  float* out = (float*)d_out;
  char* ws = (char*)d_ws;

  const size_t MB = 1024 * 1024;
  u16* xb  = (u16*)(ws);              // 16 MB: x bf16 [8192][1024]
  u16* Wqb = (u16*)(ws + 16 * MB);    // 2 MB each
  u16* Wkb = (u16*)(ws + 18 * MB);
  u16* Wvb = (u16*)(ws + 20 * MB);
  u16* Wob = (u16*)(ws + 22 * MB);
  u16* Qb  = (u16*)(ws + 24 * MB);    // 16 MB (b,h,s,d), pre-scaled (log2 units)
  u16* Kb  = (u16*)(ws + 40 * MB);    // 16 MB (b,h,s,d)
  u16* VTb = (u16*)(ws + 56 * MB);    // 16 MB (b,h,d,s)
  u16* AOb = (u16*)(ws + 72 * MB);    // 16 MB (b,s,h*d)

  castall<<<6144, 256, 0, stream>>>(x, Wq, Wk, Wv, Wo, xb, Wqb, Wkb, Wvb, Wob);

  gemm_qkv<<<1536, 256, 0, stream>>>(
      xb, Wqb, Wkb, Wvb, bq, bk, bv, Qb, Kb, VTb);

  attn_fwd<<<2048, 256, 0, stream>>>(Qb, Kb, VTb, AOb);

  gemm_out<<<512, 256, 0, stream>>>(AOb, Wob, bo, out);
}

// Round 22
// 158.350 us; speedup vs baseline: 1.2095x; 1.0362x over previous
//
#include <hip/hip_runtime.h>
#include <hip/hip_bf16.h>
#include <math.h>

#define S_LEN 2048
#define DMODEL 1024
#define NHEAD 16
#define DHEAD 64
#define BATCH 4
#define MROWS (BATCH * S_LEN)  // 8192

typedef unsigned short u16;
typedef __attribute__((ext_vector_type(4))) unsigned short u16x4;
typedef __attribute__((ext_vector_type(8))) unsigned short u16x8;
typedef __attribute__((ext_vector_type(2))) unsigned u32x2;
typedef __attribute__((ext_vector_type(4))) unsigned u32x4;
typedef __attribute__((ext_vector_type(8))) short bf16x8;
typedef __attribute__((ext_vector_type(4))) float f32x4;

__device__ __forceinline__ u16 f2bf(float f) {
  unsigned u = __float_as_uint(f);
  u += 0x7fff + ((u >> 16) & 1);  // round-to-nearest-even
  return (u16)(u >> 16);
}

__device__ __forceinline__ unsigned pkbf2(float lo, float hi) {
  // single v_cvt_pk_bf16_f32: lo -> bits[15:0], hi -> bits[31:16]
  __hip_bfloat162 h = __float22bfloat162_rn(float2{lo, hi});
  unsigned r;
  __builtin_memcpy(&r, &h, 4);
  return r;
}

__device__ __forceinline__ float exp2v(float x) {  // raw v_exp_f32 (base-2)
  float r;
  asm("v_exp_f32 %0, %1" : "=v"(r) : "v"(x));
  return r;
}

__device__ __forceinline__ f32x4 mfma16(bf16x8 a, bf16x8 b, f32x4 c) {
  return __builtin_amdgcn_mfma_f32_16x16x32_bf16(a, b, c, 0, 0, 0);
}

// ---------------- fused cast fp32 -> bf16 (x + 4 weight matrices, one launch) ----------------
__global__ __launch_bounds__(256) void castall(
    const float* __restrict__ x,
    const float* __restrict__ w0, const float* __restrict__ w1,
    const float* __restrict__ w2, const float* __restrict__ w3,
    u16* __restrict__ ox,
    u16* __restrict__ o0, u16* __restrict__ o1,
    u16* __restrict__ o2, u16* __restrict__ o3) {
  const int blk = blockIdx.x;
  const float* in;
  u16* out;
  int base;
  if (blk < 4096)      { in = x;  out = ox; base = blk; }
  else if (blk < 4608) { in = w0; out = o0; base = blk - 4096; }
  else if (blk < 5120) { in = w1; out = o1; base = blk - 4608; }
  else if (blk < 5632) { in = w2; out = o2; base = blk - 5120; }
  else                 { in = w3; out = o3; base = blk - 5632; }
  const int i = (base * 256 + threadIdx.x) * 8;
  f32x4 v0 = *(const f32x4*)(in + i);
  f32x4 v1 = *(const f32x4*)(in + i + 4);
  u16x8 o;
#pragma unroll
  for (int j = 0; j < 4; ++j) { o[j] = f2bf(v0[j]); o[4 + j] = f2bf(v1[j]); }
  *(u16x8*)(out + i) = o;
}

// ---------------- QKV projection GEMM (BK=64, swizzled LDS, T14 reg-staging) ----------------
// Within each XCD: msub = idx&7 (fast), nz = idx>>3 (slow) -> L2-retention order.
__global__ __launch_bounds__(256) void gemm_qkv(
    const u16* __restrict__ Xb,
    const u16* __restrict__ W0, const u16* __restrict__ W1, const u16* __restrict__ W2,
    const float* __restrict__ b0, const float* __restrict__ b1, const float* __restrict__ b2,
    u16* __restrict__ O0, u16* __restrict__ O1, u16* __restrict__ O2) {
  __shared__ u16 As[128 * 64];
  __shared__ u16 Bs[128 * 64];
  const int flat = blockIdx.x;
  const int xcd = flat & 7, idx = flat >> 3;   // 192 blocks per XCD
  const int msub = idx & 7;                    // m fast
  const int nz = idx >> 3;                     // (n,z) slow: 0..23
  const int ymt = xcd * 8 + msub;              // m-tile 0..63
  const int xnt = nz & 7;                      // n-tile 0..7
  const int z = nz >> 3;                       // 0..2 (Q/K/V)
  const u16* Wm = z == 0 ? W0 : (z == 1 ? W1 : W2);
  const float* bias = z == 0 ? b0 : (z == 1 ? b1 : b2);
  u16* Out = z == 0 ? O0 : (z == 1 ? O1 : O2);
  // Q pre-scale: (1/sqrt(64)) * log2(e), so attn scores are in log2 units
  const float qs = (z == 0) ? 0.18033688011112042f : 1.0f;
  const int tid = threadIdx.x;
  const int lane = tid & 63, g = lane >> 4, c = lane & 15;
  const int wave = tid >> 6;
  const int wm = wave >> 1, wn = wave & 1;
  const int bm0 = ymt * 128, bn0 = xnt * 128;

  int srow[4], scol[4];
#pragma unroll
  for (int cc = 0; cc < 4; ++cc) {
    const int ci = cc * 256 + tid;          // chunk 0..1023
    srow[cc] = ci >> 3;
    scol[cc] = ((ci & 7) ^ (srow[cc] & 7)) << 3;  // inverse-swizzled source col
  }

  f32x4 acc[4][4];
#pragma unroll
  for (int m = 0; m < 4; ++m)
#pragma unroll
    for (int n = 0; n < 4; ++n) acc[m][n] = (f32x4){0.f, 0.f, 0.f, 0.f};

  u32x4 ar0, ar1, ar2, ar3, br0, br1, br2, br3;
#define GLOAD(k0_) do {                                                        \
    ar0 = *(const u32x4*)(Xb + (size_t)(bm0 + srow[0]) * DMODEL + (k0_) + scol[0]); \
    br0 = *(const u32x4*)(Wm + (size_t)(bn0 + srow[0]) * DMODEL + (k0_) + scol[0]); \
    ar1 = *(const u32x4*)(Xb + (size_t)(bm0 + srow[1]) * DMODEL + (k0_) + scol[1]); \
    br1 = *(const u32x4*)(Wm + (size_t)(bn0 + srow[1]) * DMODEL + (k0_) + scol[1]); \
    ar2 = *(const u32x4*)(Xb + (size_t)(bm0 + srow[2]) * DMODEL + (k0_) + scol[2]); \
    br2 = *(const u32x4*)(Wm + (size_t)(bn0 + srow[2]) * DMODEL + (k0_) + scol[2]); \
    ar3 = *(const u32x4*)(Xb + (size_t)(bm0 + srow[3]) * DMODEL + (k0_) + scol[3]); \
    br3 = *(const u32x4*)(Wm + (size_t)(bn0 + srow[3]) * DMODEL + (k0_) + scol[3]); \
  } while (0)

  GLOAD(0);
  for (int k0 = 0; k0 < DMODEL; k0 += 64) {
    __syncthreads();   // prev step's LDS reads done
    *(u32x4*)((char*)As + (0 * 256 + tid) * 16) = ar0;
    *(u32x4*)((char*)Bs + (0 * 256 + tid) * 16) = br0;
    *(u32x4*)((char*)As + (1 * 256 + tid) * 16) = ar1;
    *(u32x4*)((char*)Bs + (1 * 256 + tid) * 16) = br1;
    *(u32x4*)((char*)As + (2 * 256 + tid) * 16) = ar2;
    *(u32x4*)((char*)Bs + (2 * 256 + tid) * 16) = br2;
    *(u32x4*)((char*)As + (3 * 256 + tid) * 16) = ar3;
    *(u32x4*)((char*)Bs + (3 * 256 + tid) * 16) = br3;
    __syncthreads();   // tile ready
    if (k0 + 64 < DMODEL) GLOAD(k0 + 64);  // hides under compute
#pragma unroll
    for (int ks = 0; ks < 2; ++ks) {
      bf16x8 af[4], bfr[4];
#pragma unroll
      for (int m = 0; m < 4; ++m) {
        const int arow = wm * 64 + m * 16 + c;
        af[m] = *(const bf16x8*)((const char*)As + arow * 128 +
                                 (((ks * 4 + g) ^ (arow & 7)) << 4));
      }
#pragma unroll
      for (int n = 0; n < 4; ++n) {
        const int brow = wn * 64 + n * 16 + c;
        bfr[n] = *(const bf16x8*)((const char*)Bs + brow * 128 +
                                  (((ks * 4 + g) ^ (brow & 7)) << 4));
      }
#pragma unroll
      for (int m = 0; m < 4; ++m)
#pragma unroll
        for (int n = 0; n < 4; ++n)
          acc[m][n] = mfma16(af[m], bfr[n], acc[m][n]);
    }
  }
#undef GLOAD
  if (z < 2) {
    // Q/K: (b,h,s,d) scatter
#pragma unroll
    for (int n = 0; n < 4; ++n) {
      const int coln = bn0 + wn * 64 + n * 16 + c;
      const float bn_ = bias[coln];
      const int h = coln >> 6, d = coln & 63;
#pragma unroll
      for (int m = 0; m < 4; ++m) {
#pragma unroll
        for (int r = 0; r < 4; ++r) {
          const int rowm = bm0 + wm * 64 + m * 16 + g * 4 + r;
          const int b_ = rowm >> 11, s_ = rowm & 2047;
          Out[(((size_t)(b_ * NHEAD + h) * S_LEN + s_) << 6) + d] =
              f2bf((acc[m][n][r] + bn_) * qs);
        }
      }
    }
  } else {
    // V^T: (b,h,d,s) — pack the 4 consecutive-s values into one 8B store
#pragma unroll
    for (int n = 0; n < 4; ++n) {
      const int coln = bn0 + wn * 64 + n * 16 + c;
      const float bn_ = bias[coln];
      const int h = coln >> 6, d = coln & 63;
#pragma unroll
      for (int m = 0; m < 4; ++m) {
        const int row0 = bm0 + wm * 64 + m * 16 + g * 4;
        const int b_ = row0 >> 11, s_ = row0 & 2047;
        u16x4 pk;
#pragma unroll
        for (int r = 0; r < 4; ++r) pk[r] = f2bf(acc[m][n][r] + bn_);
        *(u16x4*)(Out + ((size_t)(b_ * NHEAD + h) * DHEAD + d) * S_LEN + s_) = pk;
      }
    }
  }
}

// ---------------- output projection GEMM (BK=64, swizzled LDS, T14 reg-staging) ----------------
__global__ __launch_bounds__(256) void gemm_out(
    const u16* __restrict__ Ab, const u16* __restrict__ Wm,
    const float* __restrict__ bias, float* __restrict__ Out) {
  __shared__ u16 As[128 * 64];
  __shared__ u16 Bs[128 * 64];
  const int flat = blockIdx.x;
  const int xcd = flat & 7, idx = flat >> 3;   // 64 blocks per XCD
  const int ymt = xcd * 8 + (idx & 7);         // m fast
  const int xnt = idx >> 3;                    // n slow
  const int tid = threadIdx.x;
  const int lane = tid & 63, g = lane >> 4, c = lane & 15;
  const int wave = tid >> 6;
  const int wm = wave >> 1, wn = wave & 1;
  const int bm0 = ymt * 128, bn0 = xnt * 128;

  int srow[4], scol[4];
#pragma unroll
  for (int cc = 0; cc < 4; ++cc) {
    const int ci = cc * 256 + tid;
    srow[cc] = ci >> 3;
    scol[cc] = ((ci & 7) ^ (srow[cc] & 7)) << 3;
  }

  f32x4 acc[4][4];
#pragma unroll
  for (int m = 0; m < 4; ++m)
#pragma unroll
    for (int n = 0; n < 4; ++n) acc[m][n] = (f32x4){0.f, 0.f, 0.f, 0.f};

  u32x4 ar0, ar1, ar2, ar3, br0, br1, br2, br3;
#define GLOAD(k0_) do {                                                        \
    ar0 = *(const u32x4*)(Ab + (size_t)(bm0 + srow[0]) * DMODEL + (k0_) + scol[0]); \
    br0 = *(const u32x4*)(Wm + (size_t)(bn0 + srow[0]) * DMODEL + (k0_) + scol[0]); \
    ar1 = *(const u32x4*)(Ab + (size_t)(bm0 + srow[1]) * DMODEL + (k0_) + scol[1]); \
    br1 = *(const u32x4*)(Wm + (size_t)(bn0 + srow[1]) * DMODEL + (k0_) + scol[1]); \
    ar2 = *(const u32x4*)(Ab + (size_t)(bm0 + srow[2]) * DMODEL + (k0_) + scol[2]); \
    br2 = *(const u32x4*)(Wm + (size_t)(bn0 + srow[2]) * DMODEL + (k0_) + scol[2]); \
    ar3 = *(const u32x4*)(Ab + (size_t)(bm0 + srow[3]) * DMODEL + (k0_) + scol[3]); \
    br3 = *(const u32x4*)(Wm + (size_t)(bn0 + srow[3]) * DMODEL + (k0_) + scol[3]); \
  } while (0)

  GLOAD(0);
  for (int k0 = 0; k0 < DMODEL; k0 += 64) {
    __syncthreads();
    *(u32x4*)((char*)As + (0 * 256 + tid) * 16) = ar0;
    *(u32x4*)((char*)Bs + (0 * 256 + tid) * 16) = br0;
    *(u32x4*)((char*)As + (1 * 256 + tid) * 16) = ar1;
    *(u32x4*)((char*)Bs + (1 * 256 + tid) * 16) = br1;
    *(u32x4*)((char*)As + (2 * 256 + tid) * 16) = ar2;
    *(u32x4*)((char*)Bs + (2 * 256 + tid) * 16) = br2;
    *(u32x4*)((char*)As + (3 * 256 + tid) * 16) = ar3;
    *(u32x4*)((char*)Bs + (3 * 256 + tid) * 16) = br3;
    __syncthreads();
    if (k0 + 64 < DMODEL) GLOAD(k0 + 64);
#pragma unroll
    for (int ks = 0; ks < 2; ++ks) {
      bf16x8 af[4], bfr[4];
#pragma unroll
      for (int m = 0; m < 4; ++m) {
        const int arow = wm * 64 + m * 16 + c;
        af[m] = *(const bf16x8*)((const char*)As + arow * 128 +
                                 (((ks * 4 + g) ^ (arow & 7)) << 4));
      }
#pragma unroll
      for (int n = 0; n < 4; ++n) {
        const int brow = wn * 64 + n * 16 + c;
        bfr[n] = *(const bf16x8*)((const char*)Bs + brow * 128 +
                                  (((ks * 4 + g) ^ (brow & 7)) << 4));
      }
#pragma unroll
      for (int m = 0; m < 4; ++m)
#pragma unroll
        for (int n = 0; n < 4; ++n)
          acc[m][n] = mfma16(af[m], bfr[n], acc[m][n]);
    }
  }
#undef GLOAD
#pragma unroll
  for (int n = 0; n < 4; ++n) {
    const int coln = bn0 + wn * 64 + n * 16 + c;
    const float bn_ = bias[coln];
#pragma unroll
    for (int m = 0; m < 4; ++m) {
#pragma unroll
      for (int r = 0; r < 4; ++r) {
        const int rowm = bm0 + wm * 64 + m * 16 + g * 4 + r;
        Out[(size_t)rowm * DMODEL + coln] = acc[m][n][r] + bn_;
      }
    }
  }
}

// ---------------- causal flash attention (8 waves x 128 q-rows, shared K/V staging) ----------------
// 1024 blocks x 512 threads: xcd=flat&7, idx=flat>>3, qt16=15-(idx>>3) (heavy
// first), bh=xcd*8+(idx&7). 8 waves share one K/V tile stage (staging events
// halved vs 64-row blocks); wave w owns q-rows qb+16w..qb+16w+15. T14 staging,
// l-from-MFMA, defer-rescale (T13). Mask applies to the last TWO kv tiles
// (lower waves' rows end 64 short of the block's kv range).
__global__ __launch_bounds__(512) void attn_fwd(const u16* __restrict__ Qb,
                                                const u16* __restrict__ Kb,
                                                const u16* __restrict__ VTb,
                                                u16* __restrict__ AOb) {
  __shared__ u16 Kt[64 * 64];       // K tile [kv][d], swizzled chunks (8KB)
  __shared__ u16 Vt[64 * 64];       // V^T tile [d][kv], swizzled chunks (8KB)
  __shared__ unsigned Pl[8][16 * 36];  // per-wave P^T (18KB)
  const int tid = threadIdx.x;
  const int w = tid >> 6, lane = tid & 63, g = lane >> 4, c = lane & 15;
  const int flat = blockIdx.x;
  const int xcd = flat & 7, idx = flat >> 3;      // 128 blocks per XCD
  const int qt16 = 15 - (idx >> 3);               // heavy tiles first (128-row)
  const int bh = xcd * 8 + (idx & 7);             // 8 heads per XCD
  const size_t base = (size_t)bh * (S_LEN * DHEAD);  // same stride for K and VT
  const int b_ = bh >> 4, h = bh & 15;

  // staging chunk geometry: 512 chunks per matrix, 1 per thread
  const int row0_ = tid >> 3, colg0 = (tid & 7) ^ (row0_ & 7);

  const int qb = qt16 * 128;
  const int q = qb + w * 16 + c;   // this lane's q-row
  const bf16x8 qf0 = *(const bf16x8*)(Qb + base + (size_t)q * 64 + g * 8);
  const bf16x8 qf1 = *(const bf16x8*)(Qb + base + (size_t)q * 64 + 32 + g * 8);

  bf16x8 ones;
#pragma unroll
  for (int j = 0; j < 8; ++j) ones[j] = (short)0x3F80;  // bf16 1.0

  f32x4 oacc[4];
  f32x4 lacc = (f32x4){0.f, 0.f, 0.f, 0.f};
#pragma unroll
  for (int dt = 0; dt < 4; ++dt) oacc[dt] = (f32x4){0.f, 0.f, 0.f, 0.f};
  float m = -30000.f;

  u32x4 kreg0, vreg0;  // in-flight staging (32B/thread)
#define STAGE_LOAD(kt_) do {                                                  \
    const int kv0_ = (kt_) * 64;                                              \
    kreg0 = *(const u32x4*)(Kb + base + (size_t)(kv0_ + row0_) * 64 + colg0 * 8); \
    vreg0 = *(const u32x4*)(VTb + base + (size_t)row0_ * S_LEN + kv0_ + colg0 * 8); \
  } while (0)

  const int nt = 2 * qt16 + 2;
  STAGE_LOAD(0);
  for (int kt = 0; kt < nt; ++kt) {
    const int kv0 = kt * 64;
    __syncthreads();  // prev tile's LDS reads done before overwrite
    *(u32x4*)((char*)Kt + tid * 16) = kreg0;
    *(u32x4*)((char*)Vt + tid * 16) = vreg0;
    __syncthreads();  // tile ready
    if (kt + 1 < nt) STAGE_LOAD(kt + 1);  // issue next tile; hides under compute

    // S^T = K Q^T from swizzled LDS: s[t][r] = S[kv=kv0+16t+4g+r][q] (log2 units)
    f32x4 s[4];
#pragma unroll
    for (int t = 0; t < 4; ++t) {
      const int krow = t * 16 + c;
      const char* kbase = (const char*)Kt + krow * 128;
      bf16x8 kf0 = *(const bf16x8*)(kbase + ((g ^ (krow & 7)) * 16));
      bf16x8 kf1 = *(const bf16x8*)(kbase + (((4 + g) ^ (krow & 7)) * 16));
      f32x4 zacc = (f32x4){0.f, 0.f, 0.f, 0.f};
      zacc = mfma16(kf0, qf0, zacc);
      zacc = mfma16(kf1, qf1, zacc);
      s[t] = zacc;
    }
    if (kt >= nt - 2) {  // last two tiles can cross a wave's diagonal
#pragma unroll
      for (int t = 0; t < 4; ++t)
#pragma unroll
        for (int r = 0; r < 4; ++r)
          if (kv0 + t * 16 + 4 * g + r > q) s[t][r] = -30000.f;
    }
    // row max via max3 tree (16 values) + 2-step cross-g reduce
    const float a0 = fmaxf(fmaxf(s[0][0], s[0][1]), s[0][2]);
    const float a1 = fmaxf(fmaxf(s[0][3], s[1][0]), s[1][1]);
    const float a2 = fmaxf(fmaxf(s[1][2], s[1][3]), s[2][0]);
    const float a3 = fmaxf(fmaxf(s[2][1], s[2][2]), s[2][3]);
    const float a4 = fmaxf(fmaxf(s[3][0], s[3][1]), s[3][2]);
    float pm = fmaxf(fmaxf(fmaxf(a0, a1), a2), fmaxf(fmaxf(a3, a4), s[3][3]));
    pm = fmaxf(pm, __shfl_xor(pm, 16));
    pm = fmaxf(pm, __shfl_xor(pm, 32));
    // defer-rescale (T13): only rescale when some row grew by > 2^8
    if (__any(pm > m + 8.0f)) {
      const float mn = fmaxf(m, pm);
      const float sc = exp2v(m - mn);
      lacc *= sc;
#pragma unroll
      for (int dt = 0; dt < 4; ++dt) oacc[dt] *= sc;
      m = mn;
    }
#pragma unroll
    for (int t = 0; t < 4; ++t) {
      const float p0 = exp2v(s[t][0] - m), p1 = exp2v(s[t][1] - m);
      const float p2 = exp2v(s[t][2] - m), p3 = exp2v(s[t][3] - m);
      // P^T[q=c][kv = 16t+4g+0..3]: two v_cvt_pk_bf16_f32, one 8B store
      u32x2 pk2;
      pk2[0] = pkbf2(p0, p1);
      pk2[1] = pkbf2(p2, p3);
      *(u32x2*)&Pl[w][c * 36 + t * 8 + g * 2] = pk2;
    }

    // O^T += V^T P^T ; l += ones^T P^T (MFMA, ones A-frag: every row = sum_kv P)
#pragma unroll
    for (int kk = 0; kk < 2; ++kk) {
      const bf16x8 pb = *(const bf16x8*)&Pl[w][c * 36 + kk * 16 + g * 4];
      lacc = mfma16(ones, pb, lacc);
#pragma unroll
      for (int dt = 0; dt < 4; ++dt) {
        const int vrow = dt * 16 + c;
        const bf16x8 vf = *(const bf16x8*)((const char*)Vt + vrow * 128 +
                                           (((kk * 4 + g) ^ (vrow & 7)) * 16));
        oacc[dt] = mfma16(vf, pb, oacc[dt]);
      }
    }
  }
#undef STAGE_LOAD
  // epilogue: lane owns O[q][d = dt*16 + 4g + 0..3] -> 8B packed stores
  const float inv = 1.0f / lacc[0];
  const size_t rowbase = ((size_t)(b_ * S_LEN + q) * DMODEL) + h * 64;
#pragma unroll
  for (int dt = 0; dt < 4; ++dt) {
    u16x4 pk4;
#pragma unroll
    for (int r = 0; r < 4; ++r) pk4[r] = f2bf(oacc[dt][r] * inv);
    *(u16x4*)(AOb + rowbase + dt * 16 + 4 * g) = pk4;
  }
}

extern "C" void kernel_launch(void* const* d_in, const int* in_sizes, int n_in,
                              void* d_out, int out_size, void* d_ws, size_t ws_size,
                              hipStream_t stream) {
  const float* x  = (const float*)d_in[0];
  const float* Wq = (const float*)d_in[1];
  const float* bq = (const float*)d_in[2];
  const float* Wk = (const float*)d_in[3];
  const float* bk = (const float*)d_in[4];
  const float* Wv = (const float*)d_in[5];
  const float* bv = (const float*)d_in[6];
  const float* Wo = (const float*)d_in[7];
  const float* bo = (const float*)d_in[8];
  float* out = (float*)d_out;
  char* ws = (char*)d_ws;

  const size_t MB = 1024 * 1024;
  u16* xb  = (u16*)(ws);              // 16 MB: x bf16 [8192][1024]
  u16* Wqb = (u16*)(ws + 16 * MB);    // 2 MB each
  u16* Wkb = (u16*)(ws + 18 * MB);
  u16* Wvb = (u16*)(ws + 20 * MB);
  u16* Wob = (u16*)(ws + 22 * MB);
  u16* Qb  = (u16*)(ws + 24 * MB);    // 16 MB (b,h,s,d), pre-scaled (log2 units)
  u16* Kb  = (u16*)(ws + 40 * MB);    // 16 MB (b,h,s,d)
  u16* VTb = (u16*)(ws + 56 * MB);    // 16 MB (b,h,d,s)
  u16* AOb = (u16*)(ws + 72 * MB);    // 16 MB (b,s,h*d)

  castall<<<6144, 256, 0, stream>>>(x, Wq, Wk, Wv, Wo, xb, Wqb, Wkb, Wvb, Wob);

  gemm_qkv<<<1536, 256, 0, stream>>>(
      xb, Wqb, Wkb, Wvb, bq, bk, bv, Qb, Kb, VTb);

  attn_fwd<<<1024, 512, 0, stream>>>(Qb, Kb, VTb, AOb);

  gemm_out<<<512, 256, 0, stream>>>(AOb, Wob, bo, out);
}

// Round 23
// 158.082 us; speedup vs baseline: 1.2115x; 1.0017x over previous
//
#include <hip/hip_runtime.h>
#include <hip/hip_bf16.h>
#include <math.h>

#define S_LEN 2048
#define DMODEL 1024
#define NHEAD 16
#define DHEAD 64
#define BATCH 4
#define MROWS (BATCH * S_LEN)  // 8192

typedef unsigned short u16;
typedef __attribute__((ext_vector_type(4))) unsigned short u16x4;
typedef __attribute__((ext_vector_type(8))) unsigned short u16x8;
typedef __attribute__((ext_vector_type(2))) unsigned u32x2;
typedef __attribute__((ext_vector_type(4))) unsigned u32x4;
typedef __attribute__((ext_vector_type(8))) short bf16x8;
typedef __attribute__((ext_vector_type(4))) float f32x4;

__device__ __forceinline__ u16 f2bf(float f) {
  unsigned u = __float_as_uint(f);
  u += 0x7fff + ((u >> 16) & 1);  // round-to-nearest-even
  return (u16)(u >> 16);
}

__device__ __forceinline__ unsigned pkbf2(float lo, float hi) {
  // single v_cvt_pk_bf16_f32: lo -> bits[15:0], hi -> bits[31:16]
  __hip_bfloat162 h = __float22bfloat162_rn(float2{lo, hi});
  unsigned r;
  __builtin_memcpy(&r, &h, 4);
  return r;
}

__device__ __forceinline__ float exp2v(float x) {  // raw v_exp_f32 (base-2)
  float r;
  asm("v_exp_f32 %0, %1" : "=v"(r) : "v"(x));
  return r;
}

__device__ __forceinline__ f32x4 mfma16(bf16x8 a, bf16x8 b, f32x4 c) {
  return __builtin_amdgcn_mfma_f32_16x16x32_bf16(a, b, c, 0, 0, 0);
}

// ---------------- fused cast fp32 -> bf16 (x + 4 weight matrices, one launch) ----------------
__global__ __launch_bounds__(256) void castall(
    const float* __restrict__ x,
    const float* __restrict__ w0, const float* __restrict__ w1,
    const float* __restrict__ w2, const float* __restrict__ w3,
    u16* __restrict__ ox,
    u16* __restrict__ o0, u16* __restrict__ o1,
    u16* __restrict__ o2, u16* __restrict__ o3) {
  const int blk = blockIdx.x;
  const float* in;
  u16* out;
  int base;
  if (blk < 4096)      { in = x;  out = ox; base = blk; }
  else if (blk < 4608) { in = w0; out = o0; base = blk - 4096; }
  else if (blk < 5120) { in = w1; out = o1; base = blk - 4608; }
  else if (blk < 5632) { in = w2; out = o2; base = blk - 5120; }
  else                 { in = w3; out = o3; base = blk - 5632; }
  const int i = (base * 256 + threadIdx.x) * 8;
  f32x4 v0 = *(const f32x4*)(in + i);
  f32x4 v1 = *(const f32x4*)(in + i + 4);
  u16x8 o;
#pragma unroll
  for (int j = 0; j < 4; ++j) { o[j] = f2bf(v0[j]); o[4 + j] = f2bf(v1[j]); }
  *(u16x8*)(out + i) = o;
}

// ---------------- QKV projection GEMM (8 waves, 256x128 tile, BK=64, T14 reg-staging) ----------------
// 768 blocks x 512 threads. XCD-chunked, m fast (4 x 256-row tiles per XCD),
// (n,z) slow (L2-retention). Per K-step: one barrier pair covers 2x the MFMAs
// of the 128-tile version (barrier/drain amortization, as proven in attn R22).
__global__ __launch_bounds__(512) void gemm_qkv(
    const u16* __restrict__ Xb,
    const u16* __restrict__ W0, const u16* __restrict__ W1, const u16* __restrict__ W2,
    const float* __restrict__ b0, const float* __restrict__ b1, const float* __restrict__ b2,
    u16* __restrict__ O0, u16* __restrict__ O1, u16* __restrict__ O2) {
  __shared__ u16 As[256 * 64];   // 32KB
  __shared__ u16 Bs[128 * 64];   // 16KB
  const int flat = blockIdx.x;
  const int xcd = flat & 7, idx = flat >> 3;   // 96 blocks per XCD
  const int msub = idx & 3;                    // m fast (4 per XCD)
  const int nz = idx >> 2;                     // (n,z) slow: 0..23
  const int ymt = xcd * 4 + msub;              // 256-row m-tile 0..31
  const int xnt = nz & 7;                      // n-tile 0..7
  const int z = nz >> 3;                       // 0..2 (Q/K/V)
  const u16* Wm = z == 0 ? W0 : (z == 1 ? W1 : W2);
  const float* bias = z == 0 ? b0 : (z == 1 ? b1 : b2);
  u16* Out = z == 0 ? O0 : (z == 1 ? O1 : O2);
  // Q pre-scale: (1/sqrt(64)) * log2(e), so attn scores are in log2 units
  const float qs = (z == 0) ? 0.18033688011112042f : 1.0f;
  const int tid = threadIdx.x;
  const int lane = tid & 63, g = lane >> 4, c = lane & 15;
  const int wave = tid >> 6;                   // 0..7
  const int wm = wave >> 1, wn = wave & 1;     // 4 x 2 wave grid
  const int bm0 = ymt * 256, bn0 = xnt * 128;

  // staging geometry: A = 2048 chunks (4/thread), B = 1024 chunks (2/thread)
  int arowS[4], acolS[4], browS[2], bcolS[2];
#pragma unroll
  for (int cc = 0; cc < 4; ++cc) {
    const int ci = cc * 512 + tid;
    arowS[cc] = ci >> 3;
    acolS[cc] = ((ci & 7) ^ (arowS[cc] & 7)) << 3;
  }
#pragma unroll
  for (int cc = 0; cc < 2; ++cc) {
    const int ci = cc * 512 + tid;
    browS[cc] = ci >> 3;
    bcolS[cc] = ((ci & 7) ^ (browS[cc] & 7)) << 3;
  }

  f32x4 acc[4][4];
#pragma unroll
  for (int m = 0; m < 4; ++m)
#pragma unroll
    for (int n = 0; n < 4; ++n) acc[m][n] = (f32x4){0.f, 0.f, 0.f, 0.f};

  u32x4 ar0, ar1, ar2, ar3, br0, br1;
#define GLOAD(k0_) do {                                                        \
    ar0 = *(const u32x4*)(Xb + (size_t)(bm0 + arowS[0]) * DMODEL + (k0_) + acolS[0]); \
    ar1 = *(const u32x4*)(Xb + (size_t)(bm0 + arowS[1]) * DMODEL + (k0_) + acolS[1]); \
    ar2 = *(const u32x4*)(Xb + (size_t)(bm0 + arowS[2]) * DMODEL + (k0_) + acolS[2]); \
    ar3 = *(const u32x4*)(Xb + (size_t)(bm0 + arowS[3]) * DMODEL + (k0_) + acolS[3]); \
    br0 = *(const u32x4*)(Wm + (size_t)(bn0 + browS[0]) * DMODEL + (k0_) + bcolS[0]); \
    br1 = *(const u32x4*)(Wm + (size_t)(bn0 + browS[1]) * DMODEL + (k0_) + bcolS[1]); \
  } while (0)

  GLOAD(0);
  for (int k0 = 0; k0 < DMODEL; k0 += 64) {
    __syncthreads();   // prev step's LDS reads done
    *(u32x4*)((char*)As + (0 * 512 + tid) * 16) = ar0;
    *(u32x4*)((char*)As + (1 * 512 + tid) * 16) = ar1;
    *(u32x4*)((char*)As + (2 * 512 + tid) * 16) = ar2;
    *(u32x4*)((char*)As + (3 * 512 + tid) * 16) = ar3;
    *(u32x4*)((char*)Bs + (0 * 512 + tid) * 16) = br0;
    *(u32x4*)((char*)Bs + (1 * 512 + tid) * 16) = br1;
    __syncthreads();   // tile ready
    if (k0 + 64 < DMODEL) GLOAD(k0 + 64);  // hides under compute
#pragma unroll
    for (int ks = 0; ks < 2; ++ks) {
      bf16x8 af[4], bfr[4];
#pragma unroll
      for (int m = 0; m < 4; ++m) {
        const int arow = wm * 64 + m * 16 + c;
        af[m] = *(const bf16x8*)((const char*)As + arow * 128 +
                                 (((ks * 4 + g) ^ (arow & 7)) << 4));
      }
#pragma unroll
      for (int n = 0; n < 4; ++n) {
        const int brow = wn * 64 + n * 16 + c;
        bfr[n] = *(const bf16x8*)((const char*)Bs + brow * 128 +
                                  (((ks * 4 + g) ^ (brow & 7)) << 4));
      }
#pragma unroll
      for (int m = 0; m < 4; ++m)
#pragma unroll
        for (int n = 0; n < 4; ++n)
          acc[m][n] = mfma16(af[m], bfr[n], acc[m][n]);
    }
  }
#undef GLOAD
  if (z < 2) {
    // Q/K: (b,h,s,d) scatter
#pragma unroll
    for (int n = 0; n < 4; ++n) {
      const int coln = bn0 + wn * 64 + n * 16 + c;
      const float bn_ = bias[coln];
      const int h = coln >> 6, d = coln & 63;
#pragma unroll
      for (int m = 0; m < 4; ++m) {
#pragma unroll
        for (int r = 0; r < 4; ++r) {
          const int rowm = bm0 + wm * 64 + m * 16 + g * 4 + r;
          const int b_ = rowm >> 11, s_ = rowm & 2047;
          Out[(((size_t)(b_ * NHEAD + h) * S_LEN + s_) << 6) + d] =
              f2bf((acc[m][n][r] + bn_) * qs);
        }
      }
    }
  } else {
    // V^T: (b,h,d,s) — pack the 4 consecutive-s values into one 8B store
#pragma unroll
    for (int n = 0; n < 4; ++n) {
      const int coln = bn0 + wn * 64 + n * 16 + c;
      const float bn_ = bias[coln];
      const int h = coln >> 6, d = coln & 63;
#pragma unroll
      for (int m = 0; m < 4; ++m) {
        const int row0 = bm0 + wm * 64 + m * 16 + g * 4;
        const int b_ = row0 >> 11, s_ = row0 & 2047;
        u16x4 pk;
#pragma unroll
        for (int r = 0; r < 4; ++r) pk[r] = f2bf(acc[m][n][r] + bn_);
        *(u16x4*)(Out + ((size_t)(b_ * NHEAD + h) * DHEAD + d) * S_LEN + s_) = pk;
      }
    }
  }
}

// ---------------- output projection GEMM (BK=64, swizzled LDS, T14 reg-staging) ----------------
__global__ __launch_bounds__(256) void gemm_out(
    const u16* __restrict__ Ab, const u16* __restrict__ Wm,
    const float* __restrict__ bias, float* __restrict__ Out) {
  __shared__ u16 As[128 * 64];
  __shared__ u16 Bs[128 * 64];
  const int flat = blockIdx.x;
  const int xcd = flat & 7, idx = flat >> 3;   // 64 blocks per XCD
  const int ymt = xcd * 8 + (idx & 7);         // m fast
  const int xnt = idx >> 3;                    // n slow
  const int tid = threadIdx.x;
  const int lane = tid & 63, g = lane >> 4, c = lane & 15;
  const int wave = tid >> 6;
  const int wm = wave >> 1, wn = wave & 1;
  const int bm0 = ymt * 128, bn0 = xnt * 128;

  int srow[4], scol[4];
#pragma unroll
  for (int cc = 0; cc < 4; ++cc) {
    const int ci = cc * 256 + tid;
    srow[cc] = ci >> 3;
    scol[cc] = ((ci & 7) ^ (srow[cc] & 7)) << 3;
  }

  f32x4 acc[4][4];
#pragma unroll
  for (int m = 0; m < 4; ++m)
#pragma unroll
    for (int n = 0; n < 4; ++n) acc[m][n] = (f32x4){0.f, 0.f, 0.f, 0.f};

  u32x4 ar0, ar1, ar2, ar3, br0, br1, br2, br3;
#define GLOAD(k0_) do {                                                        \
    ar0 = *(const u32x4*)(Ab + (size_t)(bm0 + srow[0]) * DMODEL + (k0_) + scol[0]); \
    br0 = *(const u32x4*)(Wm + (size_t)(bn0 + srow[0]) * DMODEL + (k0_) + scol[0]); \
    ar1 = *(const u32x4*)(Ab + (size_t)(bm0 + srow[1]) * DMODEL + (k0_) + scol[1]); \
    br1 = *(const u32x4*)(Wm + (size_t)(bn0 + srow[1]) * DMODEL + (k0_) + scol[1]); \
    ar2 = *(const u32x4*)(Ab + (size_t)(bm0 + srow[2]) * DMODEL + (k0_) + scol[2]); \
    br2 = *(const u32x4*)(Wm + (size_t)(bn0 + srow[2]) * DMODEL + (k0_) + scol[2]); \
    ar3 = *(const u32x4*)(Ab + (size_t)(bm0 + srow[3]) * DMODEL + (k0_) + scol[3]); \
    br3 = *(const u32x4*)(Wm + (size_t)(bn0 + srow[3]) * DMODEL + (k0_) + scol[3]); \
  } while (0)

  GLOAD(0);
  for (int k0 = 0; k0 < DMODEL; k0 += 64) {
    __syncthreads();
    *(u32x4*)((char*)As + (0 * 256 + tid) * 16) = ar0;
    *(u32x4*)((char*)Bs + (0 * 256 + tid) * 16) = br0;
    *(u32x4*)((char*)As + (1 * 256 + tid) * 16) = ar1;
    *(u32x4*)((char*)Bs + (1 * 256 + tid) * 16) = br1;
    *(u32x4*)((char*)As + (2 * 256 + tid) * 16) = ar2;
    *(u32x4*)((char*)Bs + (2 * 256 + tid) * 16) = br2;
    *(u32x4*)((char*)As + (3 * 256 + tid) * 16) = ar3;
    *(u32x4*)((char*)Bs + (3 * 256 + tid) * 16) = br3;
    __syncthreads();
    if (k0 + 64 < DMODEL) GLOAD(k0 + 64);
#pragma unroll
    for (int ks = 0; ks < 2; ++ks) {
      bf16x8 af[4], bfr[4];
#pragma unroll
      for (int m = 0; m < 4; ++m) {
        const int arow = wm * 64 + m * 16 + c;
        af[m] = *(const bf16x8*)((const char*)As + arow * 128 +
                                 (((ks * 4 + g) ^ (arow & 7)) << 4));
      }
#pragma unroll
      for (int n = 0; n < 4; ++n) {
        const int brow = wn * 64 + n * 16 + c;
        bfr[n] = *(const bf16x8*)((const char*)Bs + brow * 128 +
                                  (((ks * 4 + g) ^ (brow & 7)) << 4));
      }
#pragma unroll
      for (int m = 0; m < 4; ++m)
#pragma unroll
        for (int n = 0; n < 4; ++n)
          acc[m][n] = mfma16(af[m], bfr[n], acc[m][n]);
    }
  }
#undef GLOAD
#pragma unroll
  for (int n = 0; n < 4; ++n) {
    const int coln = bn0 + wn * 64 + n * 16 + c;
    const float bn_ = bias[coln];
#pragma unroll
    for (int m = 0; m < 4; ++m) {
#pragma unroll
      for (int r = 0; r < 4; ++r) {
        const int rowm = bm0 + wm * 64 + m * 16 + g * 4 + r;
        Out[(size_t)rowm * DMODEL + coln] = acc[m][n][r] + bn_;
      }
    }
  }
}

// ---------------- causal flash attention (8 waves x 128 q-rows, shared K/V staging) ----------------
__global__ __launch_bounds__(512) void attn_fwd(const u16* __restrict__ Qb,
                                                const u16* __restrict__ Kb,
                                                const u16* __restrict__ VTb,
                                                u16* __restrict__ AOb) {
  __shared__ u16 Kt[64 * 64];       // K tile [kv][d], swizzled chunks (8KB)
  __shared__ u16 Vt[64 * 64];       // V^T tile [d][kv], swizzled chunks (8KB)
  __shared__ unsigned Pl[8][16 * 36];  // per-wave P^T (18KB)
  const int tid = threadIdx.x;
  const int w = tid >> 6, lane = tid & 63, g = lane >> 4, c = lane & 15;
  const int flat = blockIdx.x;
  const int xcd = flat & 7, idx = flat >> 3;      // 128 blocks per XCD
  const int qt16 = 15 - (idx >> 3);               // heavy tiles first (128-row)
  const int bh = xcd * 8 + (idx & 7);             // 8 heads per XCD
  const size_t base = (size_t)bh * (S_LEN * DHEAD);  // same stride for K and VT
  const int b_ = bh >> 4, h = bh & 15;

  // staging chunk geometry: 512 chunks per matrix, 1 per thread
  const int row0_ = tid >> 3, colg0 = (tid & 7) ^ (row0_ & 7);

  const int qb = qt16 * 128;
  const int q = qb + w * 16 + c;   // this lane's q-row
  const bf16x8 qf0 = *(const bf16x8*)(Qb + base + (size_t)q * 64 + g * 8);
  const bf16x8 qf1 = *(const bf16x8*)(Qb + base + (size_t)q * 64 + 32 + g * 8);

  bf16x8 ones;
#pragma unroll
  for (int j = 0; j < 8; ++j) ones[j] = (short)0x3F80;  // bf16 1.0

  f32x4 oacc[4];
  f32x4 lacc = (f32x4){0.f, 0.f, 0.f, 0.f};
#pragma unroll
  for (int dt = 0; dt < 4; ++dt) oacc[dt] = (f32x4){0.f, 0.f, 0.f, 0.f};
  float m = -30000.f;

  u32x4 kreg0, vreg0;  // in-flight staging (32B/thread)
#define STAGE_LOAD(kt_) do {                                                  \
    const int kv0_ = (kt_) * 64;                                              \
    kreg0 = *(const u32x4*)(Kb + base + (size_t)(kv0_ + row0_) * 64 + colg0 * 8); \
    vreg0 = *(const u32x4*)(VTb + base + (size_t)row0_ * S_LEN + kv0_ + colg0 * 8); \
  } while (0)

  const int nt = 2 * qt16 + 2;
  STAGE_LOAD(0);
  for (int kt = 0; kt < nt; ++kt) {
    const int kv0 = kt * 64;
    __syncthreads();  // prev tile's LDS reads done before overwrite
    *(u32x4*)((char*)Kt + tid * 16) = kreg0;
    *(u32x4*)((char*)Vt + tid * 16) = vreg0;
    __syncthreads();  // tile ready
    if (kt + 1 < nt) STAGE_LOAD(kt + 1);  // issue next tile; hides under compute

    // S^T = K Q^T from swizzled LDS: s[t][r] = S[kv=kv0+16t+4g+r][q] (log2 units)
    f32x4 s[4];
#pragma unroll
    for (int t = 0; t < 4; ++t) {
      const int krow = t * 16 + c;
      const char* kbase = (const char*)Kt + krow * 128;
      bf16x8 kf0 = *(const bf16x8*)(kbase + ((g ^ (krow & 7)) * 16));
      bf16x8 kf1 = *(const bf16x8*)(kbase + (((4 + g) ^ (krow & 7)) * 16));
      f32x4 zacc = (f32x4){0.f, 0.f, 0.f, 0.f};
      zacc = mfma16(kf0, qf0, zacc);
      zacc = mfma16(kf1, qf1, zacc);
      s[t] = zacc;
    }
    if (kt >= nt - 2) {  // last two tiles can cross a wave's diagonal
#pragma unroll
      for (int t = 0; t < 4; ++t)
#pragma unroll
        for (int r = 0; r < 4; ++r)
          if (kv0 + t * 16 + 4 * g + r > q) s[t][r] = -30000.f;
    }
    // row max via max3 tree (16 values) + 2-step cross-g reduce
    const float a0 = fmaxf(fmaxf(s[0][0], s[0][1]), s[0][2]);
    const float a1 = fmaxf(fmaxf(s[0][3], s[1][0]), s[1][1]);
    const float a2 = fmaxf(fmaxf(s[1][2], s[1][3]), s[2][0]);
    const float a3 = fmaxf(fmaxf(s[2][1], s[2][2]), s[2][3]);
    const float a4 = fmaxf(fmaxf(s[3][0], s[3][1]), s[3][2]);
    float pm = fmaxf(fmaxf(fmaxf(a0, a1), a2), fmaxf(fmaxf(a3, a4), s[3][3]));
    pm = fmaxf(pm, __shfl_xor(pm, 16));
    pm = fmaxf(pm, __shfl_xor(pm, 32));
    // defer-rescale (T13): only rescale when some row grew by > 2^8
    if (__any(pm > m + 8.0f)) {
      const float mn = fmaxf(m, pm);
      const float sc = exp2v(m - mn);
      lacc *= sc;
#pragma unroll
      for (int dt = 0; dt < 4; ++dt) oacc[dt] *= sc;
      m = mn;
    }
#pragma unroll
    for (int t = 0; t < 4; ++t) {
      const float p0 = exp2v(s[t][0] - m), p1 = exp2v(s[t][1] - m);
      const float p2 = exp2v(s[t][2] - m), p3 = exp2v(s[t][3] - m);
      // P^T[q=c][kv = 16t+4g+0..3]: two v_cvt_pk_bf16_f32, one 8B store
      u32x2 pk2;
      pk2[0] = pkbf2(p0, p1);
      pk2[1] = pkbf2(p2, p3);
      *(u32x2*)&Pl[w][c * 36 + t * 8 + g * 2] = pk2;
    }

    // O^T += V^T P^T ; l += ones^T P^T (MFMA, ones A-frag: every row = sum_kv P)
#pragma unroll
    for (int kk = 0; kk < 2; ++kk) {
      const bf16x8 pb = *(const bf16x8*)&Pl[w][c * 36 + kk * 16 + g * 4];
      lacc = mfma16(ones, pb, lacc);
#pragma unroll
      for (int dt = 0; dt < 4; ++dt) {
        const int vrow = dt * 16 + c;
        const bf16x8 vf = *(const bf16x8*)((const char*)Vt + vrow * 128 +
                                           (((kk * 4 + g) ^ (vrow & 7)) * 16));
        oacc[dt] = mfma16(vf, pb, oacc[dt]);
      }
    }
  }
#undef STAGE_LOAD
  // epilogue: lane owns O[q][d = dt*16 + 4g + 0..3] -> 8B packed stores
  const float inv = 1.0f / lacc[0];
  const size_t rowbase = ((size_t)(b_ * S_LEN + q) * DMODEL) + h * 64;
#pragma unroll
  for (int dt = 0; dt < 4; ++dt) {
    u16x4 pk4;
#pragma unroll
    for (int r = 0; r < 4; ++r) pk4[r] = f2bf(oacc[dt][r] * inv);
    *(u16x4*)(AOb + rowbase + dt * 16 + 4 * g) = pk4;
  }
}

extern "C" void kernel_launch(void* const* d_in, const int* in_sizes, int n_in,
                              void* d_out, int out_size, void* d_ws, size_t ws_size,
                              hipStream_t stream) {
  const float* x  = (const float*)d_in[0];
  const float* Wq = (const float*)d_in[1];
  const float* bq = (const float*)d_in[2];
  const float* Wk = (const float*)d_in[3];
  const float* bk = (const float*)d_in[4];
  const float* Wv = (const float*)d_in[5];
  const float* bv = (const float*)d_in[6];
  const float* Wo = (const float*)d_in[7];
  const float* bo = (const float*)d_in[8];
  float* out = (float*)d_out;
  char* ws = (char*)d_ws;

  const size_t MB = 1024 * 1024;
  u16* xb  = (u16*)(ws);              // 16 MB: x bf16 [8192][1024]
  u16* Wqb = (u16*)(ws + 16 * MB);    // 2 MB each
  u16* Wkb = (u16*)(ws + 18 * MB);
  u16* Wvb = (u16*)(ws + 20 * MB);
  u16* Wob = (u16*)(ws + 22 * MB);
  u16* Qb  = (u16*)(ws + 24 * MB);    // 16 MB (b,h,s,d), pre-scaled (log2 units)
  u16* Kb  = (u16*)(ws + 40 * MB);    // 16 MB (b,h,s,d)
  u16* VTb = (u16*)(ws + 56 * MB);    // 16 MB (b,h,d,s)
  u16* AOb = (u16*)(ws + 72 * MB);    // 16 MB (b,s,h*d)

  castall<<<6144, 256, 0, stream>>>(x, Wq, Wk, Wv, Wo, xb, Wqb, Wkb, Wvb, Wob);

  gemm_qkv<<<768, 512, 0, stream>>>(
      xb, Wqb, Wkb, Wvb, bq, bk, bv, Qb, Kb, VTb);

  attn_fwd<<<1024, 512, 0, stream>>>(Qb, Kb, VTb, AOb);

  gemm_out<<<512, 256, 0, stream>>>(AOb, Wob, bo, out);
}